// Round 7
// baseline (1891.498 us; speedup 1.0000x reference)
//
#include <hip/hip_runtime.h>
#include <hip/hip_fp16.h>

#define N_USERS 80000
#define N_ITEMS 30000
#define N_TOTAL 110000
#define DD 64
#define NNZ_ADJ 2000000
#define NNZ_MM 300000

// row-partition divisors: 8 equal partitions (8*13750 = 110000, 8*3750 = 30000)
#define PART_ADJ 13750
#define PART_MM  3750

// per-(partition,xcd-class) bin capacities: mean 31250 / 4688, +28% / +49% slack
#define BINCAP_ADJ 40000
#define BINCAP_MM  7000

typedef float          f32x4 __attribute__((ext_vector_type(4)));
typedef unsigned short u16x4 __attribute__((ext_vector_type(4)));

// ---------------- non-temporal access helpers -------------------------------
// NT ONLY for truly read-once/write-once streams. Round-6 lesson: gfx950 nt
// still allocates (LRU hint) — it softens but does not prevent eviction, so
// data with downstream reuse (ego16/cur16, ep slices) must use CACHED ops.

__device__ __forceinline__ int   ntl(const int* p)   { return __builtin_nontemporal_load(p); }
__device__ __forceinline__ float ntl(const float* p) { return __builtin_nontemporal_load(p); }
__device__ __forceinline__ int2  ntl2(const int2* p)
{
    union { long long l; int2 v; } u;
    u.l = __builtin_nontemporal_load(reinterpret_cast<const long long*>(p));
    return u.v;
}
__device__ __forceinline__ void nts(float* p, float v) { __builtin_nontemporal_store(v, p); }

__device__ __forceinline__ unsigned short f2h(float f)
{
    __half h = __float2half(f);
    return *reinterpret_cast<unsigned short*>(&h);
}

// ---------------- diagnostic sentinel ---------------------------------------

__global__ void k_sentinel(float* out, float v)
{
    if (threadIdx.x == 0 && blockIdx.x == 0) out[0] = v;
}

// ======================= CSR construction ===================================
// Two-phase binned build (round 7):
//   Phase A: single NT pass over the edge stream; count cnt[r]; wave-ballot
//            compaction appends packed edges to bin (mat, p, x=blockIdx&7).
//            Append-only writes are time-local -> no write amplification;
//            per-x bins keep the tail line on one XCD.
//   Phase B: partition-local scatter: class-p blocks read bins (mat,p,*)
//            sequentially and scatter into the L2-resident ep slice.

__global__ __launch_bounds__(256) void k_count_bin(
    const int* __restrict__ ar, const int* __restrict__ ac, const float* __restrict__ av,
    const int* __restrict__ ir, const int* __restrict__ ic, const float* __restrict__ iv,
    const int* __restrict__ tr, const int* __restrict__ tc, const float* __restrict__ tv,
    int* __restrict__ ca, int* __restrict__ ci, int* __restrict__ ct,
    int* __restrict__ bin_cnt,
    int2* __restrict__ bins_adj, int2* __restrict__ bins_img, int2* __restrict__ bins_txt)
{
    const int x    = blockIdx.x & 7;
    const int lane = threadIdx.x & 63;
    const unsigned long long lt = (lane == 63) ? 0x7fffffffffffffffull
                                               : (((unsigned long long)1 << lane) - 1);
    const int total = NNZ_ADJ + 2 * NNZ_MM;

    for (int i = blockIdx.x * blockDim.x + threadIdx.x; i < total;
         i += gridDim.x * blockDim.x) {
        int m, r, c; float v;
        if (i < NNZ_ADJ) {
            m = 0; r = ntl(ar + i); c = ntl(ac + i); v = ntl(av + i);
        } else if (i < NNZ_ADJ + NNZ_MM) {
            const int j = i - NNZ_ADJ;
            m = 1; r = ntl(ir + j); c = ntl(ic + j); v = ntl(iv + j);
        } else {
            const int j = i - NNZ_ADJ - NNZ_MM;
            m = 2; r = ntl(tr + j); c = ntl(tc + j); v = ntl(tv + j);
        }
        const int lim = (m == 0) ? N_TOTAL : N_ITEMS;
        const bool valid = ((unsigned)r < (unsigned)lim) && ((unsigned)c < (unsigned)lim);
        int p = 0, packed = 0;
        if (valid) {
            atomicAdd(((m == 0) ? ca : (m == 1) ? ci : ct) + r, 1);
            if (m == 0) { p = r / PART_ADJ; packed = ((r - p * PART_ADJ) << 17) | c; }
            else        { p = r / PART_MM;  packed = ((r - p * PART_MM)  << 15) | c; }
        }

        // ballot-compacted append, one leader atomic per (mat,partition) group
        #pragma unroll 1
        for (int mq = 0; mq < 3; ++mq) {
            #pragma unroll 1
            for (int pq = 0; pq < 8; ++pq) {
                const bool ing = valid && (m == mq) && (p == pq);
                const unsigned long long mask = __ballot(ing);
                if (mask == 0ull) continue;
                const int ldr = (int)__ffsll((unsigned long long)mask) - 1;
                int base = 0;
                if (lane == ldr)
                    base = atomicAdd(bin_cnt + (mq * 8 + pq) * 8 + x, (int)__popcll(mask));
                base = __shfl(base, ldr);
                if (ing) {
                    const int cap = (mq == 0) ? BINCAP_ADJ : BINCAP_MM;
                    int2* b = (mq == 0) ? bins_adj : (mq == 1) ? bins_img : bins_txt;
                    int idx = base + (int)__popcll(mask & lt);
                    if (idx < cap)
                        b[(size_t)(pq * 8 + x) * cap + idx] = make_int2(packed, __float_as_int(v));
                }
            }
        }
    }
}

// Phase B: segments [0,1536)=adj, [1536,1792)=img, [1792,2048)=txt; within a
// segment p = local&7 (segment bases divisible by 8 keep p == hw XCD class).
__global__ __launch_bounds__(256) void k_scatB(
    const int* __restrict__ bin_cnt,
    const int2* __restrict__ bins_adj, const int2* __restrict__ bins_img,
    const int2* __restrict__ bins_txt,
    int* __restrict__ oa, int* __restrict__ oi, int* __restrict__ ot,
    int2* __restrict__ ea, int2* __restrict__ ei, int2* __restrict__ et)
{
    int m, p, slot, nslots, cap, part, cbits;
    const int2* bins; int* off; int2* ep;
    if (blockIdx.x < 1536) {
        const int l = blockIdx.x;
        m = 0; p = l & 7; slot = l >> 3; nslots = 192;
        bins = bins_adj; cap = BINCAP_ADJ; part = PART_ADJ; cbits = 17; off = oa; ep = ea;
    } else if (blockIdx.x < 1792) {
        const int l = blockIdx.x - 1536;
        m = 1; p = l & 7; slot = l >> 3; nslots = 32;
        bins = bins_img; cap = BINCAP_MM; part = PART_MM; cbits = 15; off = oi; ep = ei;
    } else {
        const int l = blockIdx.x - 1792;
        m = 2; p = l & 7; slot = l >> 3; nslots = 32;
        bins = bins_txt; cap = BINCAP_MM; part = PART_MM; cbits = 15; off = ot; ep = et;
    }
    const int cmask = (1 << cbits) - 1;

    for (int xx = 0; xx < 8; ++xx) {
        const int n = min(bin_cnt[(m * 8 + p) * 8 + xx], cap);
        const int2* src = bins + (size_t)(p * 8 + xx) * cap;
        for (int i = slot * blockDim.x + threadIdx.x; i < n; i += nslots * blockDim.x) {
            const int2 e = ntl2(src + i);
            const int r = p * part + (int)(((unsigned)e.x) >> cbits);
            const int c = e.x & cmask;
            const int pos = atomicAdd(off + r, 1);
            ep[pos] = make_int2(c, e.y);     // cached store into L2-resident slice
        }
    }
}

// ---- legacy single-kernel build (fallback when ws has no bin region) -------

__global__ __launch_bounds__(256) void k_count_all(
    const int* __restrict__ ar, const int* __restrict__ ir,
    const int* __restrict__ tr,
    int* __restrict__ ca, int* __restrict__ ci, int* __restrict__ ct)
{
    const int total = NNZ_ADJ + 2 * NNZ_MM;
    for (int i = blockIdx.x * blockDim.x + threadIdx.x; i < total;
         i += gridDim.x * blockDim.x) {
        int r, lim; int* c;
        if (i < NNZ_ADJ)               { r = ntl(ar + i);                      c = ca; lim = N_TOTAL; }
        else if (i < NNZ_ADJ + NNZ_MM) { r = ntl(ir + (i - NNZ_ADJ));          c = ci; lim = N_ITEMS; }
        else                           { r = ntl(tr + (i - NNZ_ADJ - NNZ_MM)); c = ct; lim = N_ITEMS; }
        if ((unsigned)r < (unsigned)lim) atomicAdd(c + r, 1);
    }
}

__global__ __launch_bounds__(256) void k_scatter_all(
    const int* __restrict__ ar, const int* __restrict__ ac, const float* __restrict__ av,
    const int* __restrict__ ir, const int* __restrict__ ic, const float* __restrict__ iv,
    const int* __restrict__ tr, const int* __restrict__ tc, const float* __restrict__ tv,
    int* __restrict__ oa, int* __restrict__ oi, int* __restrict__ ot,
    int2* __restrict__ ea, int2* __restrict__ ei, int2* __restrict__ et)
{
    const int p     = blockIdx.x & 7;
    const int b8    = blockIdx.x >> 3;
    const int nb8   = gridDim.x >> 3;
    const int total = NNZ_ADJ + 2 * NNZ_MM;
    const int step  = nb8 * blockDim.x;

    for (int i0 = b8 * blockDim.x + threadIdx.x; i0 < total; i0 += step * 4) {
        #pragma unroll
        for (int u = 0; u < 4; ++u) {
            const int i = i0 + u * step;
            if (i >= total) break;
            int r, c, lim, part; float v; int* off; int2* ep;
            if (i < NNZ_ADJ) {
                r = ntl(ar + i);
                part = r / PART_ADJ;
                if (part != p) continue;
                c = ntl(ac + i); v = ntl(av + i); off = oa; ep = ea; lim = N_TOTAL;
            } else if (i < NNZ_ADJ + NNZ_MM) {
                const int j = i - NNZ_ADJ;
                r = ntl(ir + j);
                part = r / PART_MM;
                if (part != p) continue;
                c = ntl(ic + j); v = ntl(iv + j); off = oi; ep = ei; lim = N_ITEMS;
            } else {
                const int j = i - NNZ_ADJ - NNZ_MM;
                r = ntl(tr + j);
                part = r / PART_MM;
                if (part != p) continue;
                c = ntl(tc + j); v = ntl(tv + j); off = ot; ep = et; lim = N_ITEMS;
            }
            if ((unsigned)r >= (unsigned)lim || (unsigned)c >= (unsigned)lim) continue;
            const int pos = atomicAdd(&off[r], 1);
            ep[pos] = make_int2(c, __float_as_int(v));
        }
    }
}

struct ScanArg { const int4* cnt; int* rp; int* off; int n; };

// 3 blocks, one per matrix; 8 elems/thread via int4; n must be divisible by 8.
__global__ __launch_bounds__(1024) void k_scan(ScanArg a0, ScanArg a1, ScanArg a2)
{
    ScanArg A = (blockIdx.x == 0) ? a0 : (blockIdx.x == 1) ? a1 : a2;
    __shared__ int swav[16];
    __shared__ int carry;
    const int lane = threadIdx.x & 63;
    const int wid  = threadIdx.x >> 6;
    if (threadIdx.x == 0) carry = 0;
    __syncthreads();

    for (int base = 0; base < A.n; base += 8192) {
        const int i0 = base + threadIdx.x * 8;
        int4 va = make_int4(0, 0, 0, 0), vb = make_int4(0, 0, 0, 0);
        if (i0 < A.n) { va = A.cnt[i0 >> 2]; vb = A.cnt[(i0 >> 2) + 1]; }
        const int tsum = va.x + va.y + va.z + va.w + vb.x + vb.y + vb.z + vb.w;

        int x = tsum;
        #pragma unroll
        for (int o = 1; o < 64; o <<= 1) {
            int t = __shfl_up(x, o);
            if (lane >= o) x += t;
        }
        if (lane == 63) swav[wid] = x;
        __syncthreads();
        if (wid == 0) {
            int y = (lane < 16) ? swav[lane] : 0;
            #pragma unroll
            for (int o = 1; o < 16; o <<= 1) {
                int t = __shfl_up(y, o);
                if (lane >= o) y += t;
            }
            if (lane < 16) swav[lane] = y;
        }
        __syncthreads();
        const int wbase = (wid > 0) ? swav[wid - 1] : 0;
        int e = carry + wbase + (x - tsum);

        int4 pa, pb;
        pa.x = e;            pa.y = pa.x + va.x;  pa.z = pa.y + va.y;  pa.w = pa.z + va.z;
        pb.x = pa.w + va.w;  pb.y = pb.x + vb.x;  pb.z = pb.y + vb.y;  pb.w = pb.z + vb.z;
        if (i0 < A.n) {
            ((int4*)A.rp)[i0 >> 2]        = pa;
            ((int4*)A.rp)[(i0 >> 2) + 1]  = pb;
            ((int4*)A.off)[i0 >> 2]       = pa;
            ((int4*)A.off)[(i0 >> 2) + 1] = pb;
        }
        const int tot = swav[15];
        __syncthreads();
        if (threadIdx.x == 0) carry += tot;
        __syncthreads();
    }
    if (threadIdx.x == 0) A.rp[A.n] = carry;
}

// ================== gather-table abstraction ================================
// UNIFORM base + lane member (round 6): col index arrives as an SGPR via
// readlane, so the gather compiles to saddr-form global_load.

struct TabF32 {
    const float* x; int lane;
    typedef float Raw;
    __device__ __forceinline__ Raw raw(int c) const { return x[(size_t)c * DD + lane]; }
    __device__ __forceinline__ static float cvt(Raw r) { return r; }
};
struct TabF16 {
    const unsigned short* x; int lane;
    typedef unsigned short Raw;
    __device__ __forceinline__ Raw raw(int c) const { return x[(size_t)c * DD + lane]; }
    __device__ __forceinline__ static float cvt(Raw r) {
        __half h; *reinterpret_cast<unsigned short*>(&h) = r;
        return __half2float(h);
    }
};
struct TabEgo {   // f32 fallback for layer-1 (split user/item tables)
    const float* u; const float* it; int lane;
    typedef float Raw;
    __device__ __forceinline__ Raw raw(int c) const {
        const float* b = (c < N_USERS) ? u + (size_t)c * DD
                                       : it + (size_t)(c - N_USERS) * DD;
        return b[lane];
    }
    __device__ __forceinline__ static float cvt(Raw r) { return r; }
};

// fp16 conversion of [user_emb; item_emb] -> ego16. CACHED stores: ego16 is
// gathered by the next two kernels (round-6 lesson: NT would evict it).
__global__ __launch_bounds__(256) void k_cvt(const float* __restrict__ ue,
                                             const float* __restrict__ ie,
                                             unsigned short* __restrict__ out)
{
    const int n0 = N_USERS * DD / 4;
    const int n1 = N_TOTAL * DD / 4;
    for (int i = blockIdx.x * blockDim.x + threadIdx.x; i < n1;
         i += gridDim.x * blockDim.x) {
        const f32x4 v = (i < n0)
            ? __builtin_nontemporal_load(((const f32x4*)ue) + i)
            : __builtin_nontemporal_load(((const f32x4*)ie) + (i - n0));
        u16x4 o;
        o.x = f2h(v.x); o.y = f2h(v.y); o.z = f2h(v.z); o.w = f2h(v.w);
        ((u16x4*)out)[i] = o;
    }
}

// ======================= CSR SpMM core ======================================
// Quad-row combined-range traversal (round 4) + scalar edge processing via
// readlane/readfirstlane (round 6).

template<typename T>
__device__ __forceinline__ void range8(const int2 e, int k0, int k1,
                                       const T& tab, float& acc)
{
    for (int k = k0; k < k1; k += 8) {
        float vs[8]; typename T::Raw xs[8];
        #pragma unroll
        for (int s = 0; s < 8; ++s) {
            const bool ok = (k + s) < k1;           // wave-uniform
            const int  ks = ok ? (k + s) : 0;       // valid lane id
            const int  cc = __builtin_amdgcn_readlane(e.x, ks);   // SGPR col
            const int  vv = __builtin_amdgcn_readlane(e.y, ks);   // SGPR val
            vs[s] = ok ? __int_as_float(vv) : 0.f;
            xs[s] = tab.raw(ok ? cc : 0);           // saddr gather
        }
        #pragma unroll
        for (int s = 0; s < 8; ++s) acc = fmaf(vs[s], T::cvt(xs[s]), acc);
    }
}

template<typename T>
__device__ __forceinline__ void csr_rows4(const int* __restrict__ rp,
                                          const int2* __restrict__ ep,
                                          const T& tab, int r0, int lane,
                                          float& oA, float& oB, float& oC, float& oD)
{
    const int4 qv = *(const int4*)(rp + r0);  // rp 16B-aligned, r0 % 4 == 0
    const int q0 = __builtin_amdgcn_readfirstlane(qv.x);
    const int q1 = __builtin_amdgcn_readfirstlane(qv.y);
    const int q2 = __builtin_amdgcn_readfirstlane(qv.z);
    const int q3 = __builtin_amdgcn_readfirstlane(qv.w);
    const int e4 = __builtin_amdgcn_readfirstlane(rp[r0 + 4]);
    float aA = 0.f, aB = 0.f, aC = 0.f, aD = 0.f;
    for (int j = q0; j < e4; j += 64) {
        const int cnt = min(64, e4 - j);
        int2 e = make_int2(0, 0);
        if (lane < cnt) e = ntl2(ep + j + lane);
        const int b1 = min(max(q1 - j, 0), cnt);
        const int b2 = min(max(q2 - j, 0), cnt);
        const int b3 = min(max(q3 - j, 0), cnt);
        range8(e, 0,  b1,  tab, aA);
        range8(e, b1, b2,  tab, aB);
        range8(e, b2, b3,  tab, aC);
        range8(e, b3, cnt, tab, aD);
    }
    oA = aA; oB = aB; oC = aC; oD = aD;
}

// -------- modality SpMM + attention fused: 4 items per wave -----------------

template<typename T>
__global__ __launch_bounds__(256) void k_mm_q(
    const int* __restrict__ rp_i, const int2* __restrict__ ep_i,
    const int* __restrict__ rp_t, const int2* __restrict__ ep_t,
    T tab,
    const float* __restrict__ Wq1, const float* __restrict__ bq1, const float* __restrict__ wq2,
    float* __restrict__ out_img, float* __restrict__ out_txt, float* __restrict__ out_h)
{
    __shared__ float sW[DD * DD];
    __shared__ float sb[DD];
    __shared__ float sq[DD];
    for (int i = threadIdx.x; i < DD * DD; i += blockDim.x) sW[i] = Wq1[i];
    if (threadIdx.x < DD) {
        sb[threadIdx.x] = bq1[threadIdx.x];
        sq[threadIdx.x] = wq2[threadIdx.x];
    }
    __syncthreads();

    const int lane = threadIdx.x & 63;
    const int i0 = (blockIdx.x * 4 + (threadIdx.x >> 6)) * 4;
    if (i0 >= N_ITEMS) return;
    tab.lane = lane;

    float iv[4], tv[4];
    csr_rows4(rp_i, ep_i, tab, i0, lane, iv[0], iv[1], iv[2], iv[3]);
    csr_rows4(rp_t, ep_t, tab, i0, lane, tv[0], tv[1], tv[2], tv[3]);
    #pragma unroll
    for (int q = 0; q < 4; ++q) {
        const size_t p = (size_t)(i0 + q) * DD + lane;
        nts(out_img + p, iv[q]);
        nts(out_txt + p, tv[q]);
    }

    // 8-stream MLP (4 items x {img, txt})
    float A0[4], A1[4];
    #pragma unroll
    for (int q = 0; q < 4; ++q) { A0[q] = sb[lane]; A1[q] = sb[lane]; }
    #pragma unroll 4
    for (int k = 0; k < DD; ++k) {
        const float w = sW[k * DD + lane];
        #pragma unroll
        for (int q = 0; q < 4; ++q) {
            A0[q] = fmaf(__shfl(iv[q], k), w, A0[q]);
            A1[q] = fmaf(__shfl(tv[q], k), w, A1[q]);
        }
    }
    #pragma unroll
    for (int q = 0; q < 4; ++q) {
        float si = tanhf(A0[q]) * sq[lane];
        float st = tanhf(A1[q]) * sq[lane];
        #pragma unroll
        for (int off = 32; off; off >>= 1) {
            si += __shfl_xor(si, off);
            st += __shfl_xor(st, off);
        }
        const float m  = fmaxf(si, st);
        const float ei = expf(si - m), et = expf(st - m);
        const size_t p = (size_t)(i0 + q) * DD + lane;
        nts(out_h + p, (ei * iv[q] + et * tv[q]) / (ei + et));
    }
}

// -------- cur1 = A * ego, 4 rows per wave; optional fp16 shadow copy --------

template<typename T, bool W16>
__global__ __launch_bounds__(256) void k_spmm_ego_q(
    const int* __restrict__ rp, const int2* __restrict__ ep, T tab,
    float* __restrict__ out, __half* __restrict__ out16)
{
    const int lane = threadIdx.x & 63;
    const int r0 = (blockIdx.x * 4 + (threadIdx.x >> 6)) * 4;
    if (r0 >= N_TOTAL) return;
    tab.lane = lane;
    float a, b, c, d;
    csr_rows4(rp, ep, tab, r0, lane, a, b, c, d);
    const size_t p = (size_t)r0 * DD + lane;
    nts(out + p,          a);
    nts(out + p + DD,     b);
    nts(out + p + 2 * DD, c);
    nts(out + p + 3 * DD, d);
    if constexpr (W16) {
        // CACHED: cur16 is gathered by k_final_q next
        out16[p]          = __float2half(a);
        out16[p + DD]     = __float2half(b);
        out16[p + 2 * DD] = __float2half(c);
        out16[p + 3 * DD] = __float2half(d);
    }
}

// -------- fused final: role-split blocks (item blocks first, VALU-heavy) ----

#define NB_ITEM_FINAL 1875   // 1875 blocks * 4 waves * 4 rows = 30000 items
#define NB_USER_FINAL 5000   // 5000 blocks * 4 waves * 4 rows = 80000 users

template<typename T>
__global__ __launch_bounds__(256) void k_final_q(
    const int* __restrict__ rp, const int2* __restrict__ ep, T tab,
    const float* __restrict__ cur1,
    const float* __restrict__ ue, const float* __restrict__ ie,
    const float* __restrict__ h_buf,
    const float* __restrict__ Wc1, const float* __restrict__ bc1, const float* __restrict__ wc2,
    float* __restrict__ out_ug, float* __restrict__ out_ig)
{
    __shared__ float sW[DD * DD];
    __shared__ float sb[DD];
    __shared__ float sq[DD];
    const int lane = threadIdx.x & 63;
    const int wv   = threadIdx.x >> 6;
    tab.lane = lane;

    if (blockIdx.x < NB_ITEM_FINAL) {
        for (int i = threadIdx.x; i < DD * DD; i += blockDim.x) sW[i] = Wc1[i];
        if (threadIdx.x < DD) {
            sb[threadIdx.x] = bc1[threadIdx.x];
            sq[threadIdx.x] = wc2[threadIdx.x];
        }
        __syncthreads();

        const int i0 = (blockIdx.x * 4 + wv) * 4;     // item index base
        const int r0 = N_USERS + i0;
        float a[4];
        csr_rows4(rp, ep, tab, r0, lane, a[0], a[1], a[2], a[3]);

        float ig[4], hn[4];
        #pragma unroll
        for (int q = 0; q < 4; ++q) {
            const size_t pb = (size_t)(i0 + q) * DD + lane;
            const size_t gb = (size_t)(r0 + q) * DD + lane;
            ig[q] = (ntl(ie + pb) + ntl(cur1 + gb) + a[q]) * (1.0f / 3.0f);
            const float hv = ntl(h_buf + pb);
            float ss = hv * hv;
            #pragma unroll
            for (int off = 32; off; off >>= 1) ss += __shfl_xor(ss, off);
            hn[q] = hv / fmaxf(sqrtf(ss), 1e-12f);
        }

        float A0[4], A1[4];
        #pragma unroll
        for (int q = 0; q < 4; ++q) { A0[q] = sb[lane]; A1[q] = sb[lane]; }
        #pragma unroll 4
        for (int k = 0; k < DD; ++k) {
            const float w = sW[k * DD + lane];
            #pragma unroll
            for (int q = 0; q < 4; ++q) {
                A0[q] = fmaf(__shfl(ig[q], k), w, A0[q]);
                A1[q] = fmaf(__shfl(hn[q], k), w, A1[q]);
            }
        }
        #pragma unroll
        for (int q = 0; q < 4; ++q) {
            float s0 = tanhf(A0[q]) * sq[lane];
            float s1 = tanhf(A1[q]) * sq[lane];
            #pragma unroll
            for (int off = 32; off; off >>= 1) {
                s0 += __shfl_xor(s0, off);
                s1 += __shfl_xor(s1, off);
            }
            const float m  = fmaxf(s0, s1);
            const float e0 = expf(s0 - m), e1 = expf(s1 - m);
            nts(out_ig + (size_t)(i0 + q) * DD + lane,
                (e0 * ig[q] + e1 * hn[q]) / (e0 + e1));
        }
    } else {
        const int r0 = ((blockIdx.x - NB_ITEM_FINAL) * 4 + wv) * 4;   // user rows
        float a[4];
        csr_rows4(rp, ep, tab, r0, lane, a[0], a[1], a[2], a[3]);
        #pragma unroll
        for (int q = 0; q < 4; ++q) {
            const size_t gb = (size_t)(r0 + q) * DD + lane;
            nts(out_ug + gb, (ntl(ue + gb) + ntl(cur1 + gb) + a[q]) * (1.0f / 3.0f));
        }
    }
}

// ----------------------------------------------------------------------------

extern "C" void kernel_launch(void* const* d_in, const int* in_sizes, int n_in,
                              void* d_out, int out_size, void* d_ws, size_t ws_size,
                              hipStream_t stream)
{
    static const int EXP[17] = {
        N_USERS * DD, N_ITEMS * DD, DD * DD, DD, DD, DD * DD, DD, DD,
        NNZ_ADJ, NNZ_MM, NNZ_MM, NNZ_ADJ, NNZ_ADJ, NNZ_MM, NNZ_MM, NNZ_MM, NNZ_MM
    };

    float* out = (float*)d_out;

    const int OUT_EXPECT = (N_USERS + 4 * N_ITEMS) * DD;
    if (out_size != OUT_EXPECT) {
        k_sentinel<<<1, 64, 0, stream>>>(out, 5000.0f + (float)(((unsigned)out_size) >> 20));
        return;
    }
    if (n_in < 17) {
        k_sentinel<<<1, 64, 0, stream>>>(out, 1000.0f + 8.0f * (float)n_in);
        return;
    }

    int map[17];
    bool exact = true;
    for (int i = 0; i < 17; ++i) { map[i] = i; if (in_sizes[i] != EXP[i]) exact = false; }
    if (!exact) {
        bool used[64] = {false};
        for (int i = 0; i < 17; ++i) {
            int found = -1;
            for (int j = 0; j < n_in && j < 64; ++j)
                if (!used[j] && in_sizes[j] == EXP[i]) { found = j; break; }
            if (found < 0) {
                k_sentinel<<<1, 64, 0, stream>>>(out, 2000.0f + 32.0f * (float)i);
                return;
            }
            used[found] = true; map[i] = found;
        }
    }

    const float* user_emb = (const float*)d_in[map[0]];
    const float* item_emb = (const float*)d_in[map[1]];
    const float* Wq1      = (const float*)d_in[map[2]];
    const float* bq1      = (const float*)d_in[map[3]];
    const float* wq2      = (const float*)d_in[map[4]];
    const float* Wc1      = (const float*)d_in[map[5]];
    const float* bc1      = (const float*)d_in[map[6]];
    const float* wc2      = (const float*)d_in[map[7]];
    const float* adj_vals = (const float*)d_in[map[8]];
    const float* img_vals = (const float*)d_in[map[9]];
    const float* txt_vals = (const float*)d_in[map[10]];
    const int* adj_rows   = (const int*)d_in[map[11]];
    const int* adj_cols   = (const int*)d_in[map[12]];
    const int* img_rows   = (const int*)d_in[map[13]];
    const int* img_cols   = (const int*)d_in[map[14]];
    const int* txt_rows   = (const int*)d_in[map[15]];
    const int* txt_cols   = (const int*)d_in[map[16]];

    // -------- workspace layout (all 16B-aligned sections) --------
    float* cur1   = (float*)d_ws;                     // N_TOTAL*DD
    int2*  ep_adj = (int2*)(cur1 + (size_t)N_TOTAL * DD);
    int2*  ep_img = ep_adj + NNZ_ADJ;
    int2*  ep_txt = ep_img + NNZ_MM;
    int*   cnt_adj = (int*)(ep_txt + NNZ_MM);         // contiguous cnt block
    int*   cnt_img = cnt_adj + N_TOTAL;
    int*   cnt_txt = cnt_img + N_ITEMS;
    int*   rp_adj  = cnt_txt + N_ITEMS;               // padded to keep 16B align
    int*   rp_img  = rp_adj + 110004;
    int*   rp_txt  = rp_img + 30004;
    int*   off_adj = rp_txt + 30004;
    int*   off_img = off_adj + N_TOTAL;
    int*   off_txt = off_img + N_ITEMS;
    int*   bin_cnt = off_txt + N_ITEMS;               // 192 ints (3 mats x 8p x 8x)
    int*   i_end   = bin_cnt + 192;

    size_t used_b = (size_t)((char*)i_end - (char*)d_ws);
    if (ws_size < used_b) {
        k_sentinel<<<1, 64, 0, stream>>>(out, 3000.0f + (float)(ws_size >> 20));
        return;
    }
    used_b = (used_b + 15) & ~(size_t)15;
    __half* ego16 = (__half*)((char*)d_ws + used_b);          // N_TOTAL*DD halves
    __half* cur16 = ego16 + (size_t)N_TOTAL * DD;             // N_TOTAL*DD halves
    const size_t WS_FULL = used_b + 2 * (size_t)N_TOTAL * DD * sizeof(__half);
    const bool use16 = (ws_size >= WS_FULL);

    // bins OVERLAY the ego16/cur16 region (28.16 MB; bins need 27.65 MB);
    // bins are dead before k_cvt writes ego16.
    int2* bins_adj = (int2*)ego16;
    int2* bins_img = bins_adj + (size_t)64 * BINCAP_ADJ;
    int2* bins_txt = bins_img + (size_t)64 * BINCAP_MM;

    float* out_ug  = out;
    float* out_ig  = out_ug  + (size_t)N_USERS * DD;
    float* out_img = out_ig  + (size_t)N_ITEMS * DD;
    float* out_txt = out_img + (size_t)N_ITEMS * DD;
    float* out_h   = out_txt + (size_t)N_ITEMS * DD;

    // ---- CSR build ----
    hipMemsetAsync(cnt_adj, 0, (size_t)(N_TOTAL + 2 * N_ITEMS) * sizeof(int), stream);
    hipMemsetAsync(bin_cnt, 0, 192 * sizeof(int), stream);

    if (use16) {
        // two-phase binned build
        k_count_bin<<<2048, 256, 0, stream>>>(
            adj_rows, adj_cols, adj_vals, img_rows, img_cols, img_vals,
            txt_rows, txt_cols, txt_vals, cnt_adj, cnt_img, cnt_txt,
            bin_cnt, bins_adj, bins_img, bins_txt);

        ScanArg sa{(const int4*)cnt_adj, rp_adj, off_adj, N_TOTAL};
        ScanArg si{(const int4*)cnt_img, rp_img, off_img, N_ITEMS};
        ScanArg st{(const int4*)cnt_txt, rp_txt, off_txt, N_ITEMS};
        k_scan<<<3, 1024, 0, stream>>>(sa, si, st);

        k_scatB<<<2048, 256, 0, stream>>>(bin_cnt, bins_adj, bins_img, bins_txt,
                                          off_adj, off_img, off_txt,
                                          ep_adj, ep_img, ep_txt);

        // fp16 gather tables (cached stores; bins now dead)
        k_cvt<<<2048, 256, 0, stream>>>(user_emb, item_emb, (unsigned short*)ego16);

        k_mm_q<TabF16><<<1875, 256, 0, stream>>>(
            rp_img, ep_img, rp_txt, ep_txt,
            TabF16{(const unsigned short*)ego16 + (size_t)N_USERS * DD, 0},
            Wq1, bq1, wq2, out_img, out_txt, out_h);

        k_spmm_ego_q<TabF16, true><<<6875, 256, 0, stream>>>(
            rp_adj, ep_adj, TabF16{(const unsigned short*)ego16, 0}, cur1, cur16);

        k_final_q<TabF16><<<NB_ITEM_FINAL + NB_USER_FINAL, 256, 0, stream>>>(
            rp_adj, ep_adj, TabF16{(const unsigned short*)cur16, 0}, cur1,
            user_emb, item_emb, out_h, Wc1, bc1, wc2, out_ug, out_ig);
    } else {
        // legacy build + f32 quad traversal fallback
        k_count_all<<<2048, 256, 0, stream>>>(adj_rows, img_rows, txt_rows,
                                              cnt_adj, cnt_img, cnt_txt);

        ScanArg sa{(const int4*)cnt_adj, rp_adj, off_adj, N_TOTAL};
        ScanArg si{(const int4*)cnt_img, rp_img, off_img, N_ITEMS};
        ScanArg st{(const int4*)cnt_txt, rp_txt, off_txt, N_ITEMS};
        k_scan<<<3, 1024, 0, stream>>>(sa, si, st);

        k_scatter_all<<<2048, 256, 0, stream>>>(adj_rows, adj_cols, adj_vals,
                                                img_rows, img_cols, img_vals,
                                                txt_rows, txt_cols, txt_vals,
                                                off_adj, off_img, off_txt,
                                                ep_adj, ep_img, ep_txt);

        k_mm_q<TabF32><<<1875, 256, 0, stream>>>(
            rp_img, ep_img, rp_txt, ep_txt, TabF32{item_emb, 0},
            Wq1, bq1, wq2, out_img, out_txt, out_h);

        k_spmm_ego_q<TabEgo, false><<<6875, 256, 0, stream>>>(
            rp_adj, ep_adj, TabEgo{user_emb, item_emb, 0}, cur1, nullptr);

        k_final_q<TabF32><<<NB_ITEM_FINAL + NB_USER_FINAL, 256, 0, stream>>>(
            rp_adj, ep_adj, TabF32{cur1, 0}, cur1, user_emb, item_emb,
            out_h, Wc1, bc1, wc2, out_ug, out_ig);
    }
}

// Round 8
// 582.035 us; speedup vs baseline: 3.2498x; 3.2498x over previous
//
#include <hip/hip_runtime.h>
#include <hip/hip_fp16.h>

#define N_USERS 80000
#define N_ITEMS 30000
#define N_TOTAL 110000
#define DD 64
#define NNZ_ADJ 2000000
#define NNZ_MM 300000
#define TOTALE (NNZ_ADJ + 2 * NNZ_MM)

// row-partition divisors: 8 equal partitions (8*13750 = 110000, 8*3750 = 30000)
#define PART_ADJ 13750
#define PART_MM  3750

// radix-split geometry: 2048 blocks x contiguous CHUNK edges, 24 buckets
#define NBLK 2048
#define CHUNK 1270          // 2048*1270 = 2,600,960 >= TOTALE
#define NBUCK 24            // 3 matrices x 8 row-partitions

typedef float          f32x4 __attribute__((ext_vector_type(4)));
typedef unsigned short u16x4 __attribute__((ext_vector_type(4)));

// ---------------- non-temporal access helpers -------------------------------
// NT ONLY for truly read-once/write-once streams (round-6 lesson: nt is an
// LRU hint, it still allocates — reuse data must stay cached).

__device__ __forceinline__ int   ntl(const int* p)   { return __builtin_nontemporal_load(p); }
__device__ __forceinline__ float ntl(const float* p) { return __builtin_nontemporal_load(p); }
__device__ __forceinline__ int2  ntl2(const int2* p)
{
    union { long long l; int2 v; } u;
    u.l = __builtin_nontemporal_load(reinterpret_cast<const long long*>(p));
    return u.v;
}
__device__ __forceinline__ void nts(float* p, float v) { __builtin_nontemporal_store(v, p); }

__device__ __forceinline__ unsigned short f2h(float f)
{
    __half h = __float2half(f);
    return *reinterpret_cast<unsigned short*>(&h);
}

// ---------------- diagnostic sentinel ---------------------------------------

__global__ void k_sentinel(float* out, float v)
{
    if (threadIdx.x == 0 && blockIdx.x == 0) out[0] = v;
}

// ======================= CSR construction ===================================
// Round-8 radix build: hist -> scan -> split (no global atomics) -> scatD.
// Round-7 lesson: bin-slot allocation via global atomics on few counters
// serializes catastrophically; allocation must come from a scan.

__device__ __forceinline__ bool decode_edge(
    int i,
    const int* __restrict__ ar, const int* __restrict__ ac,
    const int* __restrict__ ir, const int* __restrict__ ic,
    const int* __restrict__ tr, const int* __restrict__ tc,
    int& m, int& r, int& p, int& packed)
{
    if (i < NNZ_ADJ) {
        m = 0; r = ntl(ar + i); const int c = ntl(ac + i);
        if ((unsigned)r >= (unsigned)N_TOTAL || (unsigned)c >= (unsigned)N_TOTAL) return false;
        p = r / PART_ADJ; packed = ((r - p * PART_ADJ) << 17) | c;
    } else if (i < NNZ_ADJ + NNZ_MM) {
        const int j = i - NNZ_ADJ;
        m = 1; r = ntl(ir + j); const int c = ntl(ic + j);
        if ((unsigned)r >= (unsigned)N_ITEMS || (unsigned)c >= (unsigned)N_ITEMS) return false;
        p = r / PART_MM; packed = ((r - p * PART_MM) << 15) | c;
    } else {
        const int j = i - NNZ_ADJ - NNZ_MM;
        m = 2; r = ntl(tr + j); const int c = ntl(tc + j);
        if ((unsigned)r >= (unsigned)N_ITEMS || (unsigned)c >= (unsigned)N_ITEMS) return false;
        p = r / PART_MM; packed = ((r - p * PART_MM) << 15) | c;
    }
    return true;
}

// Pass A: per-block 24-bucket histogram (LDS) + per-row CSR counts (global).
__global__ __launch_bounds__(256) void k_hist(
    const int* __restrict__ ar, const int* __restrict__ ac,
    const int* __restrict__ ir, const int* __restrict__ ic,
    const int* __restrict__ tr, const int* __restrict__ tc,
    int* __restrict__ ca, int* __restrict__ ci, int* __restrict__ ct,
    int* __restrict__ hist)
{
    __shared__ int h[NBUCK];
    if (threadIdx.x < NBUCK) h[threadIdx.x] = 0;
    __syncthreads();
    const int start = blockIdx.x * CHUNK;
    const int end   = min(start + CHUNK, TOTALE);
    for (int i = start + threadIdx.x; i < end; i += blockDim.x) {
        int m, r, p, packed;
        if (!decode_edge(i, ar, ac, ir, ic, tr, tc, m, r, p, packed)) continue;
        atomicAdd(((m == 0) ? ca : (m == 1) ? ci : ct) + r, 1);
        atomicAdd(&h[m * 8 + p], 1);
    }
    __syncthreads();
    if (threadIdx.x < NBUCK) hist[threadIdx.x * NBLK + blockIdx.x] = h[threadIdx.x];
}

// Pass C: re-read chunk, append to bucket regions at scanned bases.
// LDS cursors only — no global atomics.
__global__ __launch_bounds__(256) void k_split(
    const int* __restrict__ ar, const int* __restrict__ ac, const float* __restrict__ av,
    const int* __restrict__ ir, const int* __restrict__ ic, const float* __restrict__ iv,
    const int* __restrict__ tr, const int* __restrict__ tc, const float* __restrict__ tv,
    const int* __restrict__ hs, int2* __restrict__ binsAll)
{
    __shared__ int sb[NBUCK];
    if (threadIdx.x < NBUCK) sb[threadIdx.x] = hs[threadIdx.x * NBLK + blockIdx.x];
    __syncthreads();
    const int start = blockIdx.x * CHUNK;
    const int end   = min(start + CHUNK, TOTALE);
    for (int i = start + threadIdx.x; i < end; i += blockDim.x) {
        int m, r, p, packed;
        if (!decode_edge(i, ar, ac, ir, ic, tr, tc, m, r, p, packed)) continue;
        const float v = (m == 0) ? ntl(av + i)
                      : (m == 1) ? ntl(iv + (i - NNZ_ADJ))
                                 : ntl(tv + (i - NNZ_ADJ - NNZ_MM));
        const int idx = atomicAdd(&sb[m * 8 + p], 1);
        binsAll[idx] = make_int2(packed, __float_as_int(v));
    }
}

// Pass D: class-p blocks (XCD p via blockIdx&7) scatter bucket (m,p)'s
// contiguous region into the L2-resident ep slice. Segment bases divisible
// by 8 keep p == hw XCD class.
__global__ __launch_bounds__(256) void k_scatD(
    const int* __restrict__ hs, const int2* __restrict__ binsAll,
    int* __restrict__ oa, int* __restrict__ oi, int* __restrict__ ot,
    int2* __restrict__ ea, int2* __restrict__ ei, int2* __restrict__ et)
{
    int p, slot, nslots, q, part, cbits; int* off; int2* ep;
    if (blockIdx.x < 1536) {
        p = blockIdx.x & 7; slot = blockIdx.x >> 3; nslots = 192;
        q = p;       part = PART_ADJ; cbits = 17; off = oa; ep = ea;
    } else if (blockIdx.x < 1792) {
        const int l = blockIdx.x - 1536;
        p = l & 7; slot = l >> 3; nslots = 32;
        q = 8 + p;  part = PART_MM;  cbits = 15; off = oi; ep = ei;
    } else {
        const int l = blockIdx.x - 1792;
        p = l & 7; slot = l >> 3; nslots = 32;
        q = 16 + p; part = PART_MM;  cbits = 15; off = ot; ep = et;
    }
    const int cmask = (1 << cbits) - 1;
    const int beg  = hs[q * NBLK];
    const int endq = hs[(q < NBUCK - 1) ? (q + 1) * NBLK : NBUCK * NBLK];

    for (int i = beg + slot * blockDim.x + threadIdx.x; i < endq;
         i += nslots * blockDim.x) {
        const int2 e = ntl2(binsAll + i);
        const int r = p * part + (int)(((unsigned)e.x) >> cbits);
        const int c = e.x & cmask;
        const int pos = atomicAdd(off + r, 1);
        ep[pos] = make_int2(c, e.y);     // cached store into L2-resident slice
    }
}

// ---- legacy single-kernel build (fallback when ws lacks overlay room) ------

__global__ __launch_bounds__(256) void k_count_all(
    const int* __restrict__ ar, const int* __restrict__ ir,
    const int* __restrict__ tr,
    int* __restrict__ ca, int* __restrict__ ci, int* __restrict__ ct)
{
    const int total = TOTALE;
    for (int i = blockIdx.x * blockDim.x + threadIdx.x; i < total;
         i += gridDim.x * blockDim.x) {
        int r, lim; int* c;
        if (i < NNZ_ADJ)               { r = ntl(ar + i);                      c = ca; lim = N_TOTAL; }
        else if (i < NNZ_ADJ + NNZ_MM) { r = ntl(ir + (i - NNZ_ADJ));          c = ci; lim = N_ITEMS; }
        else                           { r = ntl(tr + (i - NNZ_ADJ - NNZ_MM)); c = ct; lim = N_ITEMS; }
        if ((unsigned)r < (unsigned)lim) atomicAdd(c + r, 1);
    }
}

__global__ __launch_bounds__(256) void k_scatter_all(
    const int* __restrict__ ar, const int* __restrict__ ac, const float* __restrict__ av,
    const int* __restrict__ ir, const int* __restrict__ ic, const float* __restrict__ iv,
    const int* __restrict__ tr, const int* __restrict__ tc, const float* __restrict__ tv,
    int* __restrict__ oa, int* __restrict__ oi, int* __restrict__ ot,
    int2* __restrict__ ea, int2* __restrict__ ei, int2* __restrict__ et)
{
    const int p     = blockIdx.x & 7;
    const int b8    = blockIdx.x >> 3;
    const int nb8   = gridDim.x >> 3;
    const int step  = nb8 * blockDim.x;

    for (int i0 = b8 * blockDim.x + threadIdx.x; i0 < TOTALE; i0 += step * 4) {
        #pragma unroll
        for (int u = 0; u < 4; ++u) {
            const int i = i0 + u * step;
            if (i >= TOTALE) break;
            int r, c, lim, part; float v; int* off; int2* ep;
            if (i < NNZ_ADJ) {
                r = ntl(ar + i);
                part = r / PART_ADJ;
                if (part != p) continue;
                c = ntl(ac + i); v = ntl(av + i); off = oa; ep = ea; lim = N_TOTAL;
            } else if (i < NNZ_ADJ + NNZ_MM) {
                const int j = i - NNZ_ADJ;
                r = ntl(ir + j);
                part = r / PART_MM;
                if (part != p) continue;
                c = ntl(ic + j); v = ntl(iv + j); off = oi; ep = ei; lim = N_ITEMS;
            } else {
                const int j = i - NNZ_ADJ - NNZ_MM;
                r = ntl(tr + j);
                part = r / PART_MM;
                if (part != p) continue;
                c = ntl(tc + j); v = ntl(tv + j); off = ot; ep = et; lim = N_ITEMS;
            }
            if ((unsigned)r >= (unsigned)lim || (unsigned)c >= (unsigned)lim) continue;
            const int pos = atomicAdd(&off[r], 1);
            ep[pos] = make_int2(c, __float_as_int(v));
        }
    }
}

struct ScanArg { const int4* cnt; int* rp; int* off; int n; };

// blocks pick a0/a1/a2; 8 elems/thread via int4; n must be divisible by 8.
__global__ __launch_bounds__(1024) void k_scan(ScanArg a0, ScanArg a1, ScanArg a2)
{
    ScanArg A = (blockIdx.x == 0) ? a0 : (blockIdx.x == 1) ? a1 : a2;
    __shared__ int swav[16];
    __shared__ int carry;
    const int lane = threadIdx.x & 63;
    const int wid  = threadIdx.x >> 6;
    if (threadIdx.x == 0) carry = 0;
    __syncthreads();

    for (int base = 0; base < A.n; base += 8192) {
        const int i0 = base + threadIdx.x * 8;
        int4 va = make_int4(0, 0, 0, 0), vb = make_int4(0, 0, 0, 0);
        if (i0 < A.n) { va = A.cnt[i0 >> 2]; vb = A.cnt[(i0 >> 2) + 1]; }
        const int tsum = va.x + va.y + va.z + va.w + vb.x + vb.y + vb.z + vb.w;

        int x = tsum;
        #pragma unroll
        for (int o = 1; o < 64; o <<= 1) {
            int t = __shfl_up(x, o);
            if (lane >= o) x += t;
        }
        if (lane == 63) swav[wid] = x;
        __syncthreads();
        if (wid == 0) {
            int y = (lane < 16) ? swav[lane] : 0;
            #pragma unroll
            for (int o = 1; o < 16; o <<= 1) {
                int t = __shfl_up(y, o);
                if (lane >= o) y += t;
            }
            if (lane < 16) swav[lane] = y;
        }
        __syncthreads();
        const int wbase = (wid > 0) ? swav[wid - 1] : 0;
        int e = carry + wbase + (x - tsum);

        int4 pa, pb;
        pa.x = e;            pa.y = pa.x + va.x;  pa.z = pa.y + va.y;  pa.w = pa.z + va.z;
        pb.x = pa.w + va.w;  pb.y = pb.x + vb.x;  pb.z = pb.y + vb.y;  pb.w = pb.z + vb.z;
        if (i0 < A.n) {
            ((int4*)A.rp)[i0 >> 2]        = pa;
            ((int4*)A.rp)[(i0 >> 2) + 1]  = pb;
            ((int4*)A.off)[i0 >> 2]       = pa;
            ((int4*)A.off)[(i0 >> 2) + 1] = pb;
        }
        const int tot = swav[15];
        __syncthreads();
        if (threadIdx.x == 0) carry += tot;
        __syncthreads();
    }
    if (threadIdx.x == 0) A.rp[A.n] = carry;
}

// ================== gather-table abstraction ================================
// UNIFORM base + lane member (round 6): col index arrives as an SGPR via
// readlane, so the gather compiles to saddr-form global_load.

struct TabF32 {
    const float* x; int lane;
    typedef float Raw;
    __device__ __forceinline__ Raw raw(int c) const { return x[(size_t)c * DD + lane]; }
    __device__ __forceinline__ static float cvt(Raw r) { return r; }
};
struct TabF16 {
    const unsigned short* x; int lane;
    typedef unsigned short Raw;
    __device__ __forceinline__ Raw raw(int c) const { return x[(size_t)c * DD + lane]; }
    __device__ __forceinline__ static float cvt(Raw r) {
        __half h; *reinterpret_cast<unsigned short*>(&h) = r;
        return __half2float(h);
    }
};
struct TabEgo {   // f32 fallback for layer-1 (split user/item tables)
    const float* u; const float* it; int lane;
    typedef float Raw;
    __device__ __forceinline__ Raw raw(int c) const {
        const float* b = (c < N_USERS) ? u + (size_t)c * DD
                                       : it + (size_t)(c - N_USERS) * DD;
        return b[lane];
    }
    __device__ __forceinline__ static float cvt(Raw r) { return r; }
};

// fp16 conversion of [user_emb; item_emb] -> ego16. CACHED stores (reused).
__global__ __launch_bounds__(256) void k_cvt(const float* __restrict__ ue,
                                             const float* __restrict__ ie,
                                             unsigned short* __restrict__ out)
{
    const int n0 = N_USERS * DD / 4;
    const int n1 = N_TOTAL * DD / 4;
    for (int i = blockIdx.x * blockDim.x + threadIdx.x; i < n1;
         i += gridDim.x * blockDim.x) {
        const f32x4 v = (i < n0)
            ? __builtin_nontemporal_load(((const f32x4*)ue) + i)
            : __builtin_nontemporal_load(((const f32x4*)ie) + (i - n0));
        u16x4 o;
        o.x = f2h(v.x); o.y = f2h(v.y); o.z = f2h(v.z); o.w = f2h(v.w);
        ((u16x4*)out)[i] = o;
    }
}

// ======================= CSR SpMM core ======================================
// Quad-row combined-range traversal (round 4) + scalar edge processing via
// readlane/readfirstlane (round 6). Unchanged from the verified 586 µs state.

template<typename T>
__device__ __forceinline__ void range8(const int2 e, int k0, int k1,
                                       const T& tab, float& acc)
{
    for (int k = k0; k < k1; k += 8) {
        float vs[8]; typename T::Raw xs[8];
        #pragma unroll
        for (int s = 0; s < 8; ++s) {
            const bool ok = (k + s) < k1;           // wave-uniform
            const int  ks = ok ? (k + s) : 0;       // valid lane id
            const int  cc = __builtin_amdgcn_readlane(e.x, ks);   // SGPR col
            const int  vv = __builtin_amdgcn_readlane(e.y, ks);   // SGPR val
            vs[s] = ok ? __int_as_float(vv) : 0.f;
            xs[s] = tab.raw(ok ? cc : 0);           // saddr gather
        }
        #pragma unroll
        for (int s = 0; s < 8; ++s) acc = fmaf(vs[s], T::cvt(xs[s]), acc);
    }
}

template<typename T>
__device__ __forceinline__ void csr_rows4(const int* __restrict__ rp,
                                          const int2* __restrict__ ep,
                                          const T& tab, int r0, int lane,
                                          float& oA, float& oB, float& oC, float& oD)
{
    const int4 qv = *(const int4*)(rp + r0);  // rp 16B-aligned, r0 % 4 == 0
    const int q0 = __builtin_amdgcn_readfirstlane(qv.x);
    const int q1 = __builtin_amdgcn_readfirstlane(qv.y);
    const int q2 = __builtin_amdgcn_readfirstlane(qv.z);
    const int q3 = __builtin_amdgcn_readfirstlane(qv.w);
    const int e4 = __builtin_amdgcn_readfirstlane(rp[r0 + 4]);
    float aA = 0.f, aB = 0.f, aC = 0.f, aD = 0.f;
    for (int j = q0; j < e4; j += 64) {
        const int cnt = min(64, e4 - j);
        int2 e = make_int2(0, 0);
        if (lane < cnt) e = ntl2(ep + j + lane);
        const int b1 = min(max(q1 - j, 0), cnt);
        const int b2 = min(max(q2 - j, 0), cnt);
        const int b3 = min(max(q3 - j, 0), cnt);
        range8(e, 0,  b1,  tab, aA);
        range8(e, b1, b2,  tab, aB);
        range8(e, b2, b3,  tab, aC);
        range8(e, b3, cnt, tab, aD);
    }
    oA = aA; oB = aB; oC = aC; oD = aD;
}

// -------- modality SpMM + attention fused: 4 items per wave -----------------

template<typename T>
__global__ __launch_bounds__(256) void k_mm_q(
    const int* __restrict__ rp_i, const int2* __restrict__ ep_i,
    const int* __restrict__ rp_t, const int2* __restrict__ ep_t,
    T tab,
    const float* __restrict__ Wq1, const float* __restrict__ bq1, const float* __restrict__ wq2,
    float* __restrict__ out_img, float* __restrict__ out_txt, float* __restrict__ out_h)
{
    __shared__ float sW[DD * DD];
    __shared__ float sb[DD];
    __shared__ float sq[DD];
    for (int i = threadIdx.x; i < DD * DD; i += blockDim.x) sW[i] = Wq1[i];
    if (threadIdx.x < DD) {
        sb[threadIdx.x] = bq1[threadIdx.x];
        sq[threadIdx.x] = wq2[threadIdx.x];
    }
    __syncthreads();

    const int lane = threadIdx.x & 63;
    const int i0 = (blockIdx.x * 4 + (threadIdx.x >> 6)) * 4;
    if (i0 >= N_ITEMS) return;
    tab.lane = lane;

    float iv[4], tv[4];
    csr_rows4(rp_i, ep_i, tab, i0, lane, iv[0], iv[1], iv[2], iv[3]);
    csr_rows4(rp_t, ep_t, tab, i0, lane, tv[0], tv[1], tv[2], tv[3]);
    #pragma unroll
    for (int q = 0; q < 4; ++q) {
        const size_t p = (size_t)(i0 + q) * DD + lane;
        nts(out_img + p, iv[q]);
        nts(out_txt + p, tv[q]);
    }

    // 8-stream MLP (4 items x {img, txt})
    float A0[4], A1[4];
    #pragma unroll
    for (int q = 0; q < 4; ++q) { A0[q] = sb[lane]; A1[q] = sb[lane]; }
    #pragma unroll 4
    for (int k = 0; k < DD; ++k) {
        const float w = sW[k * DD + lane];
        #pragma unroll
        for (int q = 0; q < 4; ++q) {
            A0[q] = fmaf(__shfl(iv[q], k), w, A0[q]);
            A1[q] = fmaf(__shfl(tv[q], k), w, A1[q]);
        }
    }
    #pragma unroll
    for (int q = 0; q < 4; ++q) {
        float si = tanhf(A0[q]) * sq[lane];
        float st = tanhf(A1[q]) * sq[lane];
        #pragma unroll
        for (int off = 32; off; off >>= 1) {
            si += __shfl_xor(si, off);
            st += __shfl_xor(st, off);
        }
        const float m  = fmaxf(si, st);
        const float ei = expf(si - m), et = expf(st - m);
        const size_t p = (size_t)(i0 + q) * DD + lane;
        nts(out_h + p, (ei * iv[q] + et * tv[q]) / (ei + et));
    }
}

// -------- cur1 = A * ego, 4 rows per wave; optional fp16 shadow copy --------

template<typename T, bool W16>
__global__ __launch_bounds__(256) void k_spmm_ego_q(
    const int* __restrict__ rp, const int2* __restrict__ ep, T tab,
    float* __restrict__ out, __half* __restrict__ out16)
{
    const int lane = threadIdx.x & 63;
    const int r0 = (blockIdx.x * 4 + (threadIdx.x >> 6)) * 4;
    if (r0 >= N_TOTAL) return;
    tab.lane = lane;
    float a, b, c, d;
    csr_rows4(rp, ep, tab, r0, lane, a, b, c, d);
    const size_t p = (size_t)r0 * DD + lane;
    nts(out + p,          a);
    nts(out + p + DD,     b);
    nts(out + p + 2 * DD, c);
    nts(out + p + 3 * DD, d);
    if constexpr (W16) {
        // CACHED: cur16 is gathered by k_final_q next
        out16[p]          = __float2half(a);
        out16[p + DD]     = __float2half(b);
        out16[p + 2 * DD] = __float2half(c);
        out16[p + 3 * DD] = __float2half(d);
    }
}

// -------- fused final: role-split blocks (item blocks first, VALU-heavy) ----

#define NB_ITEM_FINAL 1875   // 1875 blocks * 4 waves * 4 rows = 30000 items
#define NB_USER_FINAL 5000   // 5000 blocks * 4 waves * 4 rows = 80000 users

template<typename T>
__global__ __launch_bounds__(256) void k_final_q(
    const int* __restrict__ rp, const int2* __restrict__ ep, T tab,
    const float* __restrict__ cur1,
    const float* __restrict__ ue, const float* __restrict__ ie,
    const float* __restrict__ h_buf,
    const float* __restrict__ Wc1, const float* __restrict__ bc1, const float* __restrict__ wc2,
    float* __restrict__ out_ug, float* __restrict__ out_ig)
{
    __shared__ float sW[DD * DD];
    __shared__ float sb[DD];
    __shared__ float sq[DD];
    const int lane = threadIdx.x & 63;
    const int wv   = threadIdx.x >> 6;
    tab.lane = lane;

    if (blockIdx.x < NB_ITEM_FINAL) {
        for (int i = threadIdx.x; i < DD * DD; i += blockDim.x) sW[i] = Wc1[i];
        if (threadIdx.x < DD) {
            sb[threadIdx.x] = bc1[threadIdx.x];
            sq[threadIdx.x] = wc2[threadIdx.x];
        }
        __syncthreads();

        const int i0 = (blockIdx.x * 4 + wv) * 4;     // item index base
        const int r0 = N_USERS + i0;
        float a[4];
        csr_rows4(rp, ep, tab, r0, lane, a[0], a[1], a[2], a[3]);

        float ig[4], hn[4];
        #pragma unroll
        for (int q = 0; q < 4; ++q) {
            const size_t pb = (size_t)(i0 + q) * DD + lane;
            const size_t gb = (size_t)(r0 + q) * DD + lane;
            ig[q] = (ntl(ie + pb) + ntl(cur1 + gb) + a[q]) * (1.0f / 3.0f);
            const float hv = ntl(h_buf + pb);
            float ss = hv * hv;
            #pragma unroll
            for (int off = 32; off; off >>= 1) ss += __shfl_xor(ss, off);
            hn[q] = hv / fmaxf(sqrtf(ss), 1e-12f);
        }

        float A0[4], A1[4];
        #pragma unroll
        for (int q = 0; q < 4; ++q) { A0[q] = sb[lane]; A1[q] = sb[lane]; }
        #pragma unroll 4
        for (int k = 0; k < DD; ++k) {
            const float w = sW[k * DD + lane];
            #pragma unroll
            for (int q = 0; q < 4; ++q) {
                A0[q] = fmaf(__shfl(ig[q], k), w, A0[q]);
                A1[q] = fmaf(__shfl(hn[q], k), w, A1[q]);
            }
        }
        #pragma unroll
        for (int q = 0; q < 4; ++q) {
            float s0 = tanhf(A0[q]) * sq[lane];
            float s1 = tanhf(A1[q]) * sq[lane];
            #pragma unroll
            for (int off = 32; off; off >>= 1) {
                s0 += __shfl_xor(s0, off);
                s1 += __shfl_xor(s1, off);
            }
            const float m  = fmaxf(s0, s1);
            const float e0 = expf(s0 - m), e1 = expf(s1 - m);
            nts(out_ig + (size_t)(i0 + q) * DD + lane,
                (e0 * ig[q] + e1 * hn[q]) / (e0 + e1));
        }
    } else {
        const int r0 = ((blockIdx.x - NB_ITEM_FINAL) * 4 + wv) * 4;   // user rows
        float a[4];
        csr_rows4(rp, ep, tab, r0, lane, a[0], a[1], a[2], a[3]);
        #pragma unroll
        for (int q = 0; q < 4; ++q) {
            const size_t gb = (size_t)(r0 + q) * DD + lane;
            nts(out_ug + gb, (ntl(ue + gb) + ntl(cur1 + gb) + a[q]) * (1.0f / 3.0f));
        }
    }
}

// ----------------------------------------------------------------------------

extern "C" void kernel_launch(void* const* d_in, const int* in_sizes, int n_in,
                              void* d_out, int out_size, void* d_ws, size_t ws_size,
                              hipStream_t stream)
{
    static const int EXP[17] = {
        N_USERS * DD, N_ITEMS * DD, DD * DD, DD, DD, DD * DD, DD, DD,
        NNZ_ADJ, NNZ_MM, NNZ_MM, NNZ_ADJ, NNZ_ADJ, NNZ_MM, NNZ_MM, NNZ_MM, NNZ_MM
    };

    float* out = (float*)d_out;

    const int OUT_EXPECT = (N_USERS + 4 * N_ITEMS) * DD;
    if (out_size != OUT_EXPECT) {
        k_sentinel<<<1, 64, 0, stream>>>(out, 5000.0f + (float)(((unsigned)out_size) >> 20));
        return;
    }
    if (n_in < 17) {
        k_sentinel<<<1, 64, 0, stream>>>(out, 1000.0f + 8.0f * (float)n_in);
        return;
    }

    int map[17];
    bool exact = true;
    for (int i = 0; i < 17; ++i) { map[i] = i; if (in_sizes[i] != EXP[i]) exact = false; }
    if (!exact) {
        bool used[64] = {false};
        for (int i = 0; i < 17; ++i) {
            int found = -1;
            for (int j = 0; j < n_in && j < 64; ++j)
                if (!used[j] && in_sizes[j] == EXP[i]) { found = j; break; }
            if (found < 0) {
                k_sentinel<<<1, 64, 0, stream>>>(out, 2000.0f + 32.0f * (float)i);
                return;
            }
            used[found] = true; map[i] = found;
        }
    }

    const float* user_emb = (const float*)d_in[map[0]];
    const float* item_emb = (const float*)d_in[map[1]];
    const float* Wq1      = (const float*)d_in[map[2]];
    const float* bq1      = (const float*)d_in[map[3]];
    const float* wq2      = (const float*)d_in[map[4]];
    const float* Wc1      = (const float*)d_in[map[5]];
    const float* bc1      = (const float*)d_in[map[6]];
    const float* wc2      = (const float*)d_in[map[7]];
    const float* adj_vals = (const float*)d_in[map[8]];
    const float* img_vals = (const float*)d_in[map[9]];
    const float* txt_vals = (const float*)d_in[map[10]];
    const int* adj_rows   = (const int*)d_in[map[11]];
    const int* adj_cols   = (const int*)d_in[map[12]];
    const int* img_rows   = (const int*)d_in[map[13]];
    const int* img_cols   = (const int*)d_in[map[14]];
    const int* txt_rows   = (const int*)d_in[map[15]];
    const int* txt_cols   = (const int*)d_in[map[16]];

    // -------- workspace layout (all 16B-aligned sections) --------
    float* cur1   = (float*)d_ws;                     // N_TOTAL*DD
    int2*  ep_adj = (int2*)(cur1 + (size_t)N_TOTAL * DD);
    int2*  ep_img = ep_adj + NNZ_ADJ;
    int2*  ep_txt = ep_img + NNZ_MM;
    int*   cnt_adj = (int*)(ep_txt + NNZ_MM);         // contiguous cnt block
    int*   cnt_img = cnt_adj + N_TOTAL;
    int*   cnt_txt = cnt_img + N_ITEMS;
    int*   rp_adj  = cnt_txt + N_ITEMS;               // padded to keep 16B align
    int*   rp_img  = rp_adj + 110004;
    int*   rp_txt  = rp_img + 30004;
    int*   off_adj = rp_txt + 30004;
    int*   off_img = off_adj + N_TOTAL;
    int*   off_txt = off_img + N_ITEMS;
    int*   hist    = off_txt + N_ITEMS;               // NBUCK*NBLK = 49152 ints
    int*   hs      = hist + NBUCK * NBLK;             // 49153 (+3 pad) ints
    int*   i_end   = hs + NBUCK * NBLK + 4;

    size_t used_b = (size_t)((char*)i_end - (char*)d_ws);
    if (ws_size < used_b) {
        k_sentinel<<<1, 64, 0, stream>>>(out, 3000.0f + (float)(ws_size >> 20));
        return;
    }
    used_b = (used_b + 15) & ~(size_t)15;
    __half* ego16 = (__half*)((char*)d_ws + used_b);          // N_TOTAL*DD halves
    __half* cur16 = ego16 + (size_t)N_TOTAL * DD;             // N_TOTAL*DD halves
    const size_t WS_FULL = used_b + 2 * (size_t)N_TOTAL * DD * sizeof(__half);
    const bool use16 = (ws_size >= WS_FULL);

    // binsAll OVERLAYS the ego16/cur16 region (28.16 MB; needs 20.8 MB);
    // dead before k_cvt writes ego16.
    int2* binsAll = (int2*)ego16;

    float* out_ug  = out;
    float* out_ig  = out_ug  + (size_t)N_USERS * DD;
    float* out_img = out_ig  + (size_t)N_ITEMS * DD;
    float* out_txt = out_img + (size_t)N_ITEMS * DD;
    float* out_h   = out_txt + (size_t)N_ITEMS * DD;

    hipMemsetAsync(cnt_adj, 0, (size_t)(N_TOTAL + 2 * N_ITEMS) * sizeof(int), stream);

    ScanArg sa{(const int4*)cnt_adj, rp_adj, off_adj, N_TOTAL};
    ScanArg si{(const int4*)cnt_img, rp_img, off_img, N_ITEMS};
    ScanArg st{(const int4*)cnt_txt, rp_txt, off_txt, N_ITEMS};

    if (use16) {
        // ---- radix build: hist -> scans -> split -> scatD ----
        k_hist<<<NBLK, 256, 0, stream>>>(adj_rows, adj_cols, img_rows, img_cols,
                                         txt_rows, txt_cols,
                                         cnt_adj, cnt_img, cnt_txt, hist);

        k_scan<<<3, 1024, 0, stream>>>(sa, si, st);

        ScanArg sh{(const int4*)hist, hs, hs, NBUCK * NBLK};
        k_scan<<<1, 1024, 0, stream>>>(sh, sh, sh);

        k_split<<<NBLK, 256, 0, stream>>>(adj_rows, adj_cols, adj_vals,
                                          img_rows, img_cols, img_vals,
                                          txt_rows, txt_cols, txt_vals,
                                          hs, binsAll);

        k_scatD<<<2048, 256, 0, stream>>>(hs, binsAll,
                                          off_adj, off_img, off_txt,
                                          ep_adj, ep_img, ep_txt);

        // ---- fp16 gather tables (cached stores; bins now dead) ----
        k_cvt<<<2048, 256, 0, stream>>>(user_emb, item_emb, (unsigned short*)ego16);

        k_mm_q<TabF16><<<1875, 256, 0, stream>>>(
            rp_img, ep_img, rp_txt, ep_txt,
            TabF16{(const unsigned short*)ego16 + (size_t)N_USERS * DD, 0},
            Wq1, bq1, wq2, out_img, out_txt, out_h);

        k_spmm_ego_q<TabF16, true><<<6875, 256, 0, stream>>>(
            rp_adj, ep_adj, TabF16{(const unsigned short*)ego16, 0}, cur1, cur16);

        k_final_q<TabF16><<<NB_ITEM_FINAL + NB_USER_FINAL, 256, 0, stream>>>(
            rp_adj, ep_adj, TabF16{(const unsigned short*)cur16, 0}, cur1,
            user_emb, item_emb, out_h, Wc1, bc1, wc2, out_ug, out_ig);
    } else {
        // legacy build + f32 quad traversal fallback
        k_count_all<<<2048, 256, 0, stream>>>(adj_rows, img_rows, txt_rows,
                                              cnt_adj, cnt_img, cnt_txt);

        k_scan<<<3, 1024, 0, stream>>>(sa, si, st);

        k_scatter_all<<<2048, 256, 0, stream>>>(adj_rows, adj_cols, adj_vals,
                                                img_rows, img_cols, img_vals,
                                                txt_rows, txt_cols, txt_vals,
                                                off_adj, off_img, off_txt,
                                                ep_adj, ep_img, ep_txt);

        k_mm_q<TabF32><<<1875, 256, 0, stream>>>(
            rp_img, ep_img, rp_txt, ep_txt, TabF32{item_emb, 0},
            Wq1, bq1, wq2, out_img, out_txt, out_h);

        k_spmm_ego_q<TabEgo, false><<<6875, 256, 0, stream>>>(
            rp_adj, ep_adj, TabEgo{user_emb, item_emb, 0}, cur1, nullptr);

        k_final_q<TabF32><<<NB_ITEM_FINAL + NB_USER_FINAL, 256, 0, stream>>>(
            rp_adj, ep_adj, TabF32{cur1, 0}, cur1, user_emb, item_emb,
            out_h, Wc1, bc1, wc2, out_ug, out_ig);
    }
}

// Round 9
// 528.640 us; speedup vs baseline: 3.5780x; 1.1010x over previous
//
#include <hip/hip_runtime.h>
#include <hip/hip_fp16.h>

#define N_USERS 80000
#define N_ITEMS 30000
#define N_TOTAL 110000
#define DD 64
#define NNZ_ADJ 2000000
#define NNZ_MM 300000
#define TOTALE (NNZ_ADJ + 2 * NNZ_MM)

// row-partition divisors: 8 equal partitions (8*13750 = 110000, 8*3750 = 30000)
#define PART_ADJ 13750
#define PART_MM  3750

// radix-split geometry: 2048 blocks x contiguous CHUNK edges, 24 buckets
#define NBLK 2048
#define CHUNK 1270          // 2048*1270 = 2,600,960 >= TOTALE
#define NBUCK 24            // 3 matrices x 8 row-partitions

// level-2 fine buckets: 128-row windows
#define NSUB_ADJ 108        // ceil(13750/128)
#define NSUB_MM  30         // ceil(3750/128)
#define L2BLK 32            // level-2 blocks per (matrix,partition)
#define E_IMG0 (8 * NSUB_ADJ * L2BLK)            // 27648
#define E_TXT0 (E_IMG0 + 8 * NSUB_MM * L2BLK)    // 35328
#define NE2    (E_TXT0 + 8 * NSUB_MM * L2BLK)    // 43008 (divisible by 8)
#define SORT_CAP 4096       // LDS sort capacity (mean adj sub = 2327, std 48)

typedef float          f32x4 __attribute__((ext_vector_type(4)));
typedef unsigned short u16x4 __attribute__((ext_vector_type(4)));

// ---------------- non-temporal access helpers -------------------------------
// NT ONLY for truly read-once/write-once streams (round-6 lesson: nt is an
// LRU hint, it still allocates — reuse data must stay cached).
// Round-8 lesson: random sub-line stores cost ~a line of fabric write EACH,
// regardless of L2 slice residency — only sequential stores avoid it.

__device__ __forceinline__ int   ntl(const int* p)   { return __builtin_nontemporal_load(p); }
__device__ __forceinline__ float ntl(const float* p) { return __builtin_nontemporal_load(p); }
__device__ __forceinline__ int2  ntl2(const int2* p)
{
    union { long long l; int2 v; } u;
    u.l = __builtin_nontemporal_load(reinterpret_cast<const long long*>(p));
    return u.v;
}
__device__ __forceinline__ void nts(float* p, float v) { __builtin_nontemporal_store(v, p); }

__device__ __forceinline__ unsigned short f2h(float f)
{
    __half h = __float2half(f);
    return *reinterpret_cast<unsigned short*>(&h);
}

// ---------------- diagnostic sentinel ---------------------------------------

__global__ void k_sentinel(float* out, float v)
{
    if (threadIdx.x == 0 && blockIdx.x == 0) out[0] = v;
}

// ======================= CSR construction ===================================
// Round-9 build: hist -> scan -> split -> hist2 -> scan -> split2 -> sort3.
// All allocation scan-based (round-7 lesson); final ep writes fully coalesced
// via per-sub-bucket LDS counting sort (round-8 lesson).

__device__ __forceinline__ bool decode_edge(
    int i,
    const int* __restrict__ ar, const int* __restrict__ ac,
    const int* __restrict__ ir, const int* __restrict__ ic,
    const int* __restrict__ tr, const int* __restrict__ tc,
    int& m, int& r, int& p, int& packed)
{
    if (i < NNZ_ADJ) {
        m = 0; r = ntl(ar + i); const int c = ntl(ac + i);
        if ((unsigned)r >= (unsigned)N_TOTAL || (unsigned)c >= (unsigned)N_TOTAL) return false;
        p = r / PART_ADJ; packed = ((r - p * PART_ADJ) << 17) | c;
    } else if (i < NNZ_ADJ + NNZ_MM) {
        const int j = i - NNZ_ADJ;
        m = 1; r = ntl(ir + j); const int c = ntl(ic + j);
        if ((unsigned)r >= (unsigned)N_ITEMS || (unsigned)c >= (unsigned)N_ITEMS) return false;
        p = r / PART_MM; packed = ((r - p * PART_MM) << 15) | c;
    } else {
        const int j = i - NNZ_ADJ - NNZ_MM;
        m = 2; r = ntl(tr + j); const int c = ntl(tc + j);
        if ((unsigned)r >= (unsigned)N_ITEMS || (unsigned)c >= (unsigned)N_ITEMS) return false;
        p = r / PART_MM; packed = ((r - p * PART_MM) << 15) | c;
    }
    return true;
}

// Pass A: per-block 24-bucket histogram (LDS) + per-row CSR counts (global).
__global__ __launch_bounds__(256) void k_hist(
    const int* __restrict__ ar, const int* __restrict__ ac,
    const int* __restrict__ ir, const int* __restrict__ ic,
    const int* __restrict__ tr, const int* __restrict__ tc,
    int* __restrict__ ca, int* __restrict__ ci, int* __restrict__ ct,
    int* __restrict__ hist)
{
    __shared__ int h[NBUCK];
    if (threadIdx.x < NBUCK) h[threadIdx.x] = 0;
    __syncthreads();
    const int start = blockIdx.x * CHUNK;
    const int end   = min(start + CHUNK, TOTALE);
    for (int i = start + threadIdx.x; i < end; i += blockDim.x) {
        int m, r, p, packed;
        if (!decode_edge(i, ar, ac, ir, ic, tr, tc, m, r, p, packed)) continue;
        atomicAdd(((m == 0) ? ca : (m == 1) ? ci : ct) + r, 1);
        atomicAdd(&h[m * 8 + p], 1);
    }
    __syncthreads();
    if (threadIdx.x < NBUCK) hist[threadIdx.x * NBLK + blockIdx.x] = h[threadIdx.x];
}

// Pass C: re-read chunk, append to bucket regions at scanned bases.
__global__ __launch_bounds__(256) void k_split(
    const int* __restrict__ ar, const int* __restrict__ ac, const float* __restrict__ av,
    const int* __restrict__ ir, const int* __restrict__ ic, const float* __restrict__ iv,
    const int* __restrict__ tr, const int* __restrict__ tc, const float* __restrict__ tv,
    const int* __restrict__ hs, int2* __restrict__ binsAll)
{
    __shared__ int sb[NBUCK];
    if (threadIdx.x < NBUCK) sb[threadIdx.x] = hs[threadIdx.x * NBLK + blockIdx.x];
    __syncthreads();
    const int start = blockIdx.x * CHUNK;
    const int end   = min(start + CHUNK, TOTALE);
    for (int i = start + threadIdx.x; i < end; i += blockDim.x) {
        int m, r, p, packed;
        if (!decode_edge(i, ar, ac, ir, ic, tr, tc, m, r, p, packed)) continue;
        const float v = (m == 0) ? ntl(av + i)
                      : (m == 1) ? ntl(iv + (i - NNZ_ADJ))
                                 : ntl(tv + (i - NNZ_ADJ - NNZ_MM));
        const int idx = atomicAdd(&sb[m * 8 + p], 1);
        binsAll[idx] = make_int2(packed, __float_as_int(v));
    }
}

// ---- level-2: fine sub-bucketing (128-row windows) -------------------------
// 768 blocks: [0,256)=adj, [256,512)=img, [512,768)=txt; 32 blocks/(m,p).

__device__ __forceinline__ void l2_decode(int bid, int& q, int& b, int& nsub,
                                          int& cbits, int& e0)
{
    if (bid < 256)      { const int l = bid;       const int p = l >> 5; b = l & 31;
                          q = p;      nsub = NSUB_ADJ; cbits = 17; e0 = p * NSUB_ADJ * L2BLK; }
    else if (bid < 512) { const int l = bid - 256; const int p = l >> 5; b = l & 31;
                          q = 8 + p;  nsub = NSUB_MM;  cbits = 15; e0 = E_IMG0 + p * NSUB_MM * L2BLK; }
    else                { const int l = bid - 512; const int p = l >> 5; b = l & 31;
                          q = 16 + p; nsub = NSUB_MM;  cbits = 15; e0 = E_TXT0 + p * NSUB_MM * L2BLK; }
}

__global__ __launch_bounds__(256) void k_hist2(
    const int* __restrict__ hs, const int2* __restrict__ binsAll,
    int* __restrict__ hist2)
{
    __shared__ int h[NSUB_ADJ];
    int q, b, nsub, cbits, e0;
    l2_decode(blockIdx.x, q, b, nsub, cbits, e0);
    if (threadIdx.x < nsub) h[threadIdx.x] = 0;
    __syncthreads();
    const int beg = hs[q * NBLK], end = hs[(q + 1) * NBLK];
    const long long len = end - beg;
    const int c0 = beg + (int)((len * b) >> 5);
    const int c1 = beg + (int)((len * (b + 1)) >> 5);
    for (int i = c0 + threadIdx.x; i < c1; i += blockDim.x) {
        const int2 e = binsAll[i];
        atomicAdd(&h[((unsigned)e.x >> cbits) >> 7], 1);
    }
    __syncthreads();
    if (threadIdx.x < nsub) hist2[e0 + threadIdx.x * L2BLK + b] = h[threadIdx.x];
}

__global__ __launch_bounds__(256) void k_split2(
    const int* __restrict__ hs, const int* __restrict__ hs2,
    const int2* __restrict__ binsAll, int2* __restrict__ binsAll2)
{
    __shared__ int cur[NSUB_ADJ];
    int q, b, nsub, cbits, e0;
    l2_decode(blockIdx.x, q, b, nsub, cbits, e0);
    if (threadIdx.x < nsub) cur[threadIdx.x] = hs2[e0 + threadIdx.x * L2BLK + b];
    __syncthreads();
    const int beg = hs[q * NBLK], end = hs[(q + 1) * NBLK];
    const long long len = end - beg;
    const int c0 = beg + (int)((len * b) >> 5);
    const int c1 = beg + (int)((len * (b + 1)) >> 5);
    for (int i = c0 + threadIdx.x; i < c1; i += blockDim.x) {
        const int2 e = binsAll[i];
        const int s = ((unsigned)e.x >> cbits) >> 7;
        const int idx = atomicAdd(&cur[s], 1);
        binsAll2[idx] = e;   // ~nsub sequential append streams/block: lines fill
    }
}

// ---- level-3: per-sub-bucket LDS counting sort -> coalesced CSR write ------
// grid: 864 adj + 240 img + 240 txt = 1344 blocks.

__global__ __launch_bounds__(256) void k_sort3(
    const int* __restrict__ hs2, const int2* __restrict__ binsAll2,
    const int* __restrict__ rpa, const int* __restrict__ rpi, const int* __restrict__ rpt,
    int* __restrict__ oa, int* __restrict__ oi, int* __restrict__ ot,
    int2* __restrict__ ea, int2* __restrict__ ei, int2* __restrict__ et)
{
    __shared__ int2 sorted[SORT_CAP];
    __shared__ int cnt[128];
    __shared__ int bas[128];
    __shared__ int wsum[2];

    int p, s, E, cbits, partN; const int* rp; int* off; int2* ep;
    const int bid = blockIdx.x;
    if (bid < 864) {
        p = bid / NSUB_ADJ; s = bid - p * NSUB_ADJ;
        E = (p * NSUB_ADJ + s) * L2BLK; cbits = 17; partN = PART_ADJ;
        rp = rpa; off = oa; ep = ea;
    } else if (bid < 1104) {
        const int l = bid - 864; p = l / NSUB_MM; s = l - p * NSUB_MM;
        E = E_IMG0 + (p * NSUB_MM + s) * L2BLK; cbits = 15; partN = PART_MM;
        rp = rpi; off = oi; ep = ei;
    } else {
        const int l = bid - 1104; p = l / NSUB_MM; s = l - p * NSUB_MM;
        E = E_TXT0 + (p * NSUB_MM + s) * L2BLK; cbits = 15; partN = PART_MM;
        rp = rpt; off = ot; ep = et;
    }
    const int cmask = (1 << cbits) - 1;
    const int beg = hs2[E], end = hs2[E + L2BLK];
    const int n   = end - beg;
    const int r0  = p * partN + s * 128;
    const int tid = threadIdx.x;

    if (n <= SORT_CAP) {
        if (tid < 128) cnt[tid] = 0;
        __syncthreads();
        for (int i = beg + tid; i < end; i += blockDim.x) {
            const int2 e = binsAll2[i];
            atomicAdd(&cnt[((unsigned)e.x >> cbits) - s * 128], 1);
        }
        __syncthreads();
        int x = 0;
        if (tid < 128) {
            x = cnt[tid];
            #pragma unroll
            for (int o = 1; o < 64; o <<= 1) {
                int t = __shfl_up(x, o);
                if ((tid & 63) >= o) x += t;
            }
            if ((tid & 63) == 63) wsum[tid >> 6] = x;
        }
        __syncthreads();
        if (tid < 128) {
            if (tid >= 64) x += wsum[0];
            bas[tid] = x - cnt[tid];     // exclusive prefix
        }
        __syncthreads();
        if (tid < 128) cnt[tid] = 0;     // reuse as cursor
        __syncthreads();
        for (int i = beg + tid; i < end; i += blockDim.x) {
            const int2 e = binsAll2[i];
            const int rl = ((unsigned)e.x >> cbits) - s * 128;
            const int pos = bas[rl] + atomicAdd(&cnt[rl], 1);
            sorted[pos] = e;
        }
        __syncthreads();
        const int rpbase = rp[r0];
        for (int t = tid; t < n; t += blockDim.x) {
            const int2 e = sorted[t];
            ep[rpbase + t] = make_int2(e.x & cmask, e.y);   // coalesced
        }
    } else {
        // overflow fallback (statistically unreachable): per-edge cursor scatter
        for (int i = beg + tid; i < end; i += blockDim.x) {
            const int2 e = binsAll2[i];
            const int r = p * partN + (int)((unsigned)e.x >> cbits);
            const int pos = atomicAdd(off + r, 1);
            ep[pos] = make_int2(e.x & cmask, e.y);
        }
    }
}

// ---- legacy single-kernel build (fallback when ws lacks overlay room) ------

__global__ __launch_bounds__(256) void k_count_all(
    const int* __restrict__ ar, const int* __restrict__ ir,
    const int* __restrict__ tr,
    int* __restrict__ ca, int* __restrict__ ci, int* __restrict__ ct)
{
    const int total = TOTALE;
    for (int i = blockIdx.x * blockDim.x + threadIdx.x; i < total;
         i += gridDim.x * blockDim.x) {
        int r, lim; int* c;
        if (i < NNZ_ADJ)               { r = ntl(ar + i);                      c = ca; lim = N_TOTAL; }
        else if (i < NNZ_ADJ + NNZ_MM) { r = ntl(ir + (i - NNZ_ADJ));          c = ci; lim = N_ITEMS; }
        else                           { r = ntl(tr + (i - NNZ_ADJ - NNZ_MM)); c = ct; lim = N_ITEMS; }
        if ((unsigned)r < (unsigned)lim) atomicAdd(c + r, 1);
    }
}

__global__ __launch_bounds__(256) void k_scatter_all(
    const int* __restrict__ ar, const int* __restrict__ ac, const float* __restrict__ av,
    const int* __restrict__ ir, const int* __restrict__ ic, const float* __restrict__ iv,
    const int* __restrict__ tr, const int* __restrict__ tc, const float* __restrict__ tv,
    int* __restrict__ oa, int* __restrict__ oi, int* __restrict__ ot,
    int2* __restrict__ ea, int2* __restrict__ ei, int2* __restrict__ et)
{
    const int p     = blockIdx.x & 7;
    const int b8    = blockIdx.x >> 3;
    const int nb8   = gridDim.x >> 3;
    const int step  = nb8 * blockDim.x;

    for (int i0 = b8 * blockDim.x + threadIdx.x; i0 < TOTALE; i0 += step * 4) {
        #pragma unroll
        for (int u = 0; u < 4; ++u) {
            const int i = i0 + u * step;
            if (i >= TOTALE) break;
            int r, c, lim, part; float v; int* off; int2* ep;
            if (i < NNZ_ADJ) {
                r = ntl(ar + i);
                part = r / PART_ADJ;
                if (part != p) continue;
                c = ntl(ac + i); v = ntl(av + i); off = oa; ep = ea; lim = N_TOTAL;
            } else if (i < NNZ_ADJ + NNZ_MM) {
                const int j = i - NNZ_ADJ;
                r = ntl(ir + j);
                part = r / PART_MM;
                if (part != p) continue;
                c = ntl(ic + j); v = ntl(iv + j); off = oi; ep = ei; lim = N_ITEMS;
            } else {
                const int j = i - NNZ_ADJ - NNZ_MM;
                r = ntl(tr + j);
                part = r / PART_MM;
                if (part != p) continue;
                c = ntl(tc + j); v = ntl(tv + j); off = ot; ep = et; lim = N_ITEMS;
            }
            if ((unsigned)r >= (unsigned)lim || (unsigned)c >= (unsigned)lim) continue;
            const int pos = atomicAdd(&off[r], 1);
            ep[pos] = make_int2(c, __float_as_int(v));
        }
    }
}

struct ScanArg { const int4* cnt; int* rp; int* off; int n; };

// blocks pick a0/a1/a2; 8 elems/thread via int4; n must be divisible by 8.
__global__ __launch_bounds__(1024) void k_scan(ScanArg a0, ScanArg a1, ScanArg a2)
{
    ScanArg A = (blockIdx.x == 0) ? a0 : (blockIdx.x == 1) ? a1 : a2;
    __shared__ int swav[16];
    __shared__ int carry;
    const int lane = threadIdx.x & 63;
    const int wid  = threadIdx.x >> 6;
    if (threadIdx.x == 0) carry = 0;
    __syncthreads();

    for (int base = 0; base < A.n; base += 8192) {
        const int i0 = base + threadIdx.x * 8;
        int4 va = make_int4(0, 0, 0, 0), vb = make_int4(0, 0, 0, 0);
        if (i0 < A.n) { va = A.cnt[i0 >> 2]; vb = A.cnt[(i0 >> 2) + 1]; }
        const int tsum = va.x + va.y + va.z + va.w + vb.x + vb.y + vb.z + vb.w;

        int x = tsum;
        #pragma unroll
        for (int o = 1; o < 64; o <<= 1) {
            int t = __shfl_up(x, o);
            if (lane >= o) x += t;
        }
        if (lane == 63) swav[wid] = x;
        __syncthreads();
        if (wid == 0) {
            int y = (lane < 16) ? swav[lane] : 0;
            #pragma unroll
            for (int o = 1; o < 16; o <<= 1) {
                int t = __shfl_up(y, o);
                if (lane >= o) y += t;
            }
            if (lane < 16) swav[lane] = y;
        }
        __syncthreads();
        const int wbase = (wid > 0) ? swav[wid - 1] : 0;
        int e = carry + wbase + (x - tsum);

        int4 pa, pb;
        pa.x = e;            pa.y = pa.x + va.x;  pa.z = pa.y + va.y;  pa.w = pa.z + va.z;
        pb.x = pa.w + va.w;  pb.y = pb.x + vb.x;  pb.z = pb.y + vb.y;  pb.w = pb.z + vb.z;
        if (i0 < A.n) {
            ((int4*)A.rp)[i0 >> 2]        = pa;
            ((int4*)A.rp)[(i0 >> 2) + 1]  = pb;
            ((int4*)A.off)[i0 >> 2]       = pa;
            ((int4*)A.off)[(i0 >> 2) + 1] = pb;
        }
        const int tot = swav[15];
        __syncthreads();
        if (threadIdx.x == 0) carry += tot;
        __syncthreads();
    }
    if (threadIdx.x == 0) A.rp[A.n] = carry;
}

// ================== gather-table abstraction ================================
// UNIFORM base + lane member (round 6): col index arrives as an SGPR via
// readlane, so the gather compiles to saddr-form global_load.

struct TabF32 {
    const float* x; int lane;
    typedef float Raw;
    __device__ __forceinline__ Raw raw(int c) const { return x[(size_t)c * DD + lane]; }
    __device__ __forceinline__ static float cvt(Raw r) { return r; }
};
struct TabF16 {
    const unsigned short* x; int lane;
    typedef unsigned short Raw;
    __device__ __forceinline__ Raw raw(int c) const { return x[(size_t)c * DD + lane]; }
    __device__ __forceinline__ static float cvt(Raw r) {
        __half h; *reinterpret_cast<unsigned short*>(&h) = r;
        return __half2float(h);
    }
};
struct TabEgo {   // f32 fallback for layer-1 (split user/item tables)
    const float* u; const float* it; int lane;
    typedef float Raw;
    __device__ __forceinline__ Raw raw(int c) const {
        const float* b = (c < N_USERS) ? u + (size_t)c * DD
                                       : it + (size_t)(c - N_USERS) * DD;
        return b[lane];
    }
    __device__ __forceinline__ static float cvt(Raw r) { return r; }
};

// fp16 conversion of [user_emb; item_emb] -> ego16. CACHED stores (reused).
__global__ __launch_bounds__(256) void k_cvt(const float* __restrict__ ue,
                                             const float* __restrict__ ie,
                                             unsigned short* __restrict__ out)
{
    const int n0 = N_USERS * DD / 4;
    const int n1 = N_TOTAL * DD / 4;
    for (int i = blockIdx.x * blockDim.x + threadIdx.x; i < n1;
         i += gridDim.x * blockDim.x) {
        const f32x4 v = (i < n0)
            ? __builtin_nontemporal_load(((const f32x4*)ue) + i)
            : __builtin_nontemporal_load(((const f32x4*)ie) + (i - n0));
        u16x4 o;
        o.x = f2h(v.x); o.y = f2h(v.y); o.z = f2h(v.z); o.w = f2h(v.w);
        ((u16x4*)out)[i] = o;
    }
}

// ======================= CSR SpMM core ======================================
// Quad-row combined-range traversal (round 4) + scalar edge processing via
// readlane/readfirstlane (round 6). Unchanged from the verified 582 µs state.

template<typename T>
__device__ __forceinline__ void range8(const int2 e, int k0, int k1,
                                       const T& tab, float& acc)
{
    for (int k = k0; k < k1; k += 8) {
        float vs[8]; typename T::Raw xs[8];
        #pragma unroll
        for (int s = 0; s < 8; ++s) {
            const bool ok = (k + s) < k1;           // wave-uniform
            const int  ks = ok ? (k + s) : 0;       // valid lane id
            const int  cc = __builtin_amdgcn_readlane(e.x, ks);   // SGPR col
            const int  vv = __builtin_amdgcn_readlane(e.y, ks);   // SGPR val
            vs[s] = ok ? __int_as_float(vv) : 0.f;
            xs[s] = tab.raw(ok ? cc : 0);           // saddr gather
        }
        #pragma unroll
        for (int s = 0; s < 8; ++s) acc = fmaf(vs[s], T::cvt(xs[s]), acc);
    }
}

template<typename T>
__device__ __forceinline__ void csr_rows4(const int* __restrict__ rp,
                                          const int2* __restrict__ ep,
                                          const T& tab, int r0, int lane,
                                          float& oA, float& oB, float& oC, float& oD)
{
    const int4 qv = *(const int4*)(rp + r0);  // rp 16B-aligned, r0 % 4 == 0
    const int q0 = __builtin_amdgcn_readfirstlane(qv.x);
    const int q1 = __builtin_amdgcn_readfirstlane(qv.y);
    const int q2 = __builtin_amdgcn_readfirstlane(qv.z);
    const int q3 = __builtin_amdgcn_readfirstlane(qv.w);
    const int e4 = __builtin_amdgcn_readfirstlane(rp[r0 + 4]);
    float aA = 0.f, aB = 0.f, aC = 0.f, aD = 0.f;
    for (int j = q0; j < e4; j += 64) {
        const int cnt = min(64, e4 - j);
        int2 e = make_int2(0, 0);
        if (lane < cnt) e = ntl2(ep + j + lane);
        const int b1 = min(max(q1 - j, 0), cnt);
        const int b2 = min(max(q2 - j, 0), cnt);
        const int b3 = min(max(q3 - j, 0), cnt);
        range8(e, 0,  b1,  tab, aA);
        range8(e, b1, b2,  tab, aB);
        range8(e, b2, b3,  tab, aC);
        range8(e, b3, cnt, tab, aD);
    }
    oA = aA; oB = aB; oC = aC; oD = aD;
}

// -------- modality SpMM + attention fused: 4 items per wave -----------------

template<typename T>
__global__ __launch_bounds__(256) void k_mm_q(
    const int* __restrict__ rp_i, const int2* __restrict__ ep_i,
    const int* __restrict__ rp_t, const int2* __restrict__ ep_t,
    T tab,
    const float* __restrict__ Wq1, const float* __restrict__ bq1, const float* __restrict__ wq2,
    float* __restrict__ out_img, float* __restrict__ out_txt, float* __restrict__ out_h)
{
    __shared__ float sW[DD * DD];
    __shared__ float sb[DD];
    __shared__ float sq[DD];
    for (int i = threadIdx.x; i < DD * DD; i += blockDim.x) sW[i] = Wq1[i];
    if (threadIdx.x < DD) {
        sb[threadIdx.x] = bq1[threadIdx.x];
        sq[threadIdx.x] = wq2[threadIdx.x];
    }
    __syncthreads();

    const int lane = threadIdx.x & 63;
    const int i0 = (blockIdx.x * 4 + (threadIdx.x >> 6)) * 4;
    if (i0 >= N_ITEMS) return;
    tab.lane = lane;

    float iv[4], tv[4];
    csr_rows4(rp_i, ep_i, tab, i0, lane, iv[0], iv[1], iv[2], iv[3]);
    csr_rows4(rp_t, ep_t, tab, i0, lane, tv[0], tv[1], tv[2], tv[3]);
    #pragma unroll
    for (int q = 0; q < 4; ++q) {
        const size_t p = (size_t)(i0 + q) * DD + lane;
        nts(out_img + p, iv[q]);
        nts(out_txt + p, tv[q]);
    }

    // 8-stream MLP (4 items x {img, txt})
    float A0[4], A1[4];
    #pragma unroll
    for (int q = 0; q < 4; ++q) { A0[q] = sb[lane]; A1[q] = sb[lane]; }
    #pragma unroll 4
    for (int k = 0; k < DD; ++k) {
        const float w = sW[k * DD + lane];
        #pragma unroll
        for (int q = 0; q < 4; ++q) {
            A0[q] = fmaf(__shfl(iv[q], k), w, A0[q]);
            A1[q] = fmaf(__shfl(tv[q], k), w, A1[q]);
        }
    }
    #pragma unroll
    for (int q = 0; q < 4; ++q) {
        float si = tanhf(A0[q]) * sq[lane];
        float st = tanhf(A1[q]) * sq[lane];
        #pragma unroll
        for (int off = 32; off; off >>= 1) {
            si += __shfl_xor(si, off);
            st += __shfl_xor(st, off);
        }
        const float m  = fmaxf(si, st);
        const float ei = expf(si - m), et = expf(st - m);
        const size_t p = (size_t)(i0 + q) * DD + lane;
        nts(out_h + p, (ei * iv[q] + et * tv[q]) / (ei + et));
    }
}

// -------- cur1 = A * ego, 4 rows per wave; optional fp16 shadow copy --------

template<typename T, bool W16>
__global__ __launch_bounds__(256) void k_spmm_ego_q(
    const int* __restrict__ rp, const int2* __restrict__ ep, T tab,
    float* __restrict__ out, __half* __restrict__ out16)
{
    const int lane = threadIdx.x & 63;
    const int r0 = (blockIdx.x * 4 + (threadIdx.x >> 6)) * 4;
    if (r0 >= N_TOTAL) return;
    tab.lane = lane;
    float a, b, c, d;
    csr_rows4(rp, ep, tab, r0, lane, a, b, c, d);
    const size_t p = (size_t)r0 * DD + lane;
    nts(out + p,          a);
    nts(out + p + DD,     b);
    nts(out + p + 2 * DD, c);
    nts(out + p + 3 * DD, d);
    if constexpr (W16) {
        // CACHED: cur16 is gathered by k_final_q next
        out16[p]          = __float2half(a);
        out16[p + DD]     = __float2half(b);
        out16[p + 2 * DD] = __float2half(c);
        out16[p + 3 * DD] = __float2half(d);
    }
}

// -------- fused final: role-split blocks (item blocks first, VALU-heavy) ----

#define NB_ITEM_FINAL 1875   // 1875 blocks * 4 waves * 4 rows = 30000 items
#define NB_USER_FINAL 5000   // 5000 blocks * 4 waves * 4 rows = 80000 users

template<typename T>
__global__ __launch_bounds__(256) void k_final_q(
    const int* __restrict__ rp, const int2* __restrict__ ep, T tab,
    const float* __restrict__ cur1,
    const float* __restrict__ ue, const float* __restrict__ ie,
    const float* __restrict__ h_buf,
    const float* __restrict__ Wc1, const float* __restrict__ bc1, const float* __restrict__ wc2,
    float* __restrict__ out_ug, float* __restrict__ out_ig)
{
    __shared__ float sW[DD * DD];
    __shared__ float sb[DD];
    __shared__ float sq[DD];
    const int lane = threadIdx.x & 63;
    const int wv   = threadIdx.x >> 6;
    tab.lane = lane;

    if (blockIdx.x < NB_ITEM_FINAL) {
        for (int i = threadIdx.x; i < DD * DD; i += blockDim.x) sW[i] = Wc1[i];
        if (threadIdx.x < DD) {
            sb[threadIdx.x] = bc1[threadIdx.x];
            sq[threadIdx.x] = wc2[threadIdx.x];
        }
        __syncthreads();

        const int i0 = (blockIdx.x * 4 + wv) * 4;     // item index base
        const int r0 = N_USERS + i0;
        float a[4];
        csr_rows4(rp, ep, tab, r0, lane, a[0], a[1], a[2], a[3]);

        float ig[4], hn[4];
        #pragma unroll
        for (int q = 0; q < 4; ++q) {
            const size_t pb = (size_t)(i0 + q) * DD + lane;
            const size_t gb = (size_t)(r0 + q) * DD + lane;
            ig[q] = (ntl(ie + pb) + ntl(cur1 + gb) + a[q]) * (1.0f / 3.0f);
            const float hv = ntl(h_buf + pb);
            float ss = hv * hv;
            #pragma unroll
            for (int off = 32; off; off >>= 1) ss += __shfl_xor(ss, off);
            hn[q] = hv / fmaxf(sqrtf(ss), 1e-12f);
        }

        float A0[4], A1[4];
        #pragma unroll
        for (int q = 0; q < 4; ++q) { A0[q] = sb[lane]; A1[q] = sb[lane]; }
        #pragma unroll 4
        for (int k = 0; k < DD; ++k) {
            const float w = sW[k * DD + lane];
            #pragma unroll
            for (int q = 0; q < 4; ++q) {
                A0[q] = fmaf(__shfl(ig[q], k), w, A0[q]);
                A1[q] = fmaf(__shfl(hn[q], k), w, A1[q]);
            }
        }
        #pragma unroll
        for (int q = 0; q < 4; ++q) {
            float s0 = tanhf(A0[q]) * sq[lane];
            float s1 = tanhf(A1[q]) * sq[lane];
            #pragma unroll
            for (int off = 32; off; off >>= 1) {
                s0 += __shfl_xor(s0, off);
                s1 += __shfl_xor(s1, off);
            }
            const float m  = fmaxf(s0, s1);
            const float e0 = expf(s0 - m), e1 = expf(s1 - m);
            nts(out_ig + (size_t)(i0 + q) * DD + lane,
                (e0 * ig[q] + e1 * hn[q]) / (e0 + e1));
        }
    } else {
        const int r0 = ((blockIdx.x - NB_ITEM_FINAL) * 4 + wv) * 4;   // user rows
        float a[4];
        csr_rows4(rp, ep, tab, r0, lane, a[0], a[1], a[2], a[3]);
        #pragma unroll
        for (int q = 0; q < 4; ++q) {
            const size_t gb = (size_t)(r0 + q) * DD + lane;
            nts(out_ug + gb, (ntl(ue + gb) + ntl(cur1 + gb) + a[q]) * (1.0f / 3.0f));
        }
    }
}

// ----------------------------------------------------------------------------

extern "C" void kernel_launch(void* const* d_in, const int* in_sizes, int n_in,
                              void* d_out, int out_size, void* d_ws, size_t ws_size,
                              hipStream_t stream)
{
    static const int EXP[17] = {
        N_USERS * DD, N_ITEMS * DD, DD * DD, DD, DD, DD * DD, DD, DD,
        NNZ_ADJ, NNZ_MM, NNZ_MM, NNZ_ADJ, NNZ_ADJ, NNZ_MM, NNZ_MM, NNZ_MM, NNZ_MM
    };

    float* out = (float*)d_out;

    const int OUT_EXPECT = (N_USERS + 4 * N_ITEMS) * DD;
    if (out_size != OUT_EXPECT) {
        k_sentinel<<<1, 64, 0, stream>>>(out, 5000.0f + (float)(((unsigned)out_size) >> 20));
        return;
    }
    if (n_in < 17) {
        k_sentinel<<<1, 64, 0, stream>>>(out, 1000.0f + 8.0f * (float)n_in);
        return;
    }

    int map[17];
    bool exact = true;
    for (int i = 0; i < 17; ++i) { map[i] = i; if (in_sizes[i] != EXP[i]) exact = false; }
    if (!exact) {
        bool used[64] = {false};
        for (int i = 0; i < 17; ++i) {
            int found = -1;
            for (int j = 0; j < n_in && j < 64; ++j)
                if (!used[j] && in_sizes[j] == EXP[i]) { found = j; break; }
            if (found < 0) {
                k_sentinel<<<1, 64, 0, stream>>>(out, 2000.0f + 32.0f * (float)i);
                return;
            }
            used[found] = true; map[i] = found;
        }
    }

    const float* user_emb = (const float*)d_in[map[0]];
    const float* item_emb = (const float*)d_in[map[1]];
    const float* Wq1      = (const float*)d_in[map[2]];
    const float* bq1      = (const float*)d_in[map[3]];
    const float* wq2      = (const float*)d_in[map[4]];
    const float* Wc1      = (const float*)d_in[map[5]];
    const float* bc1      = (const float*)d_in[map[6]];
    const float* wc2      = (const float*)d_in[map[7]];
    const float* adj_vals = (const float*)d_in[map[8]];
    const float* img_vals = (const float*)d_in[map[9]];
    const float* txt_vals = (const float*)d_in[map[10]];
    const int* adj_rows   = (const int*)d_in[map[11]];
    const int* adj_cols   = (const int*)d_in[map[12]];
    const int* img_rows   = (const int*)d_in[map[13]];
    const int* img_cols   = (const int*)d_in[map[14]];
    const int* txt_rows   = (const int*)d_in[map[15]];
    const int* txt_cols   = (const int*)d_in[map[16]];

    // -------- workspace layout (all 16B-aligned sections) --------
    float* cur1   = (float*)d_ws;                     // N_TOTAL*DD
    int2*  ep_adj = (int2*)(cur1 + (size_t)N_TOTAL * DD);
    int2*  ep_img = ep_adj + NNZ_ADJ;
    int2*  ep_txt = ep_img + NNZ_MM;
    int*   cnt_adj = (int*)(ep_txt + NNZ_MM);         // contiguous cnt block
    int*   cnt_img = cnt_adj + N_TOTAL;
    int*   cnt_txt = cnt_img + N_ITEMS;
    int*   rp_adj  = cnt_txt + N_ITEMS;               // padded to keep 16B align
    int*   rp_img  = rp_adj + 110004;
    int*   rp_txt  = rp_img + 30004;
    int*   off_adj = rp_txt + 30004;
    int*   off_img = off_adj + N_TOTAL;
    int*   off_txt = off_img + N_ITEMS;
    int*   hist    = off_txt + N_ITEMS;               // NBUCK*NBLK = 49152 ints
    int*   hs      = hist + NBUCK * NBLK;             // 49153 (+3 pad) ints
    int*   i_end   = hs + NBUCK * NBLK + 4;

    size_t used_b = (size_t)((char*)i_end - (char*)d_ws);
    if (ws_size < used_b) {
        k_sentinel<<<1, 64, 0, stream>>>(out, 3000.0f + (float)(ws_size >> 20));
        return;
    }
    used_b = (used_b + 15) & ~(size_t)15;
    __half* ego16 = (__half*)((char*)d_ws + used_b);          // N_TOTAL*DD halves
    __half* cur16 = ego16 + (size_t)N_TOTAL * DD;             // N_TOTAL*DD halves
    const size_t WS_FULL = used_b + 2 * (size_t)N_TOTAL * DD * sizeof(__half);
    const bool use16 = (ws_size >= WS_FULL);

    // binsAll OVERLAYS the ego16/cur16 region (28.16 MB; needs 20.8 MB);
    // dead before k_cvt writes ego16.
    int2* binsAll = (int2*)ego16;

    // level-2 scratch lives in d_out (out_ug+out_ig region, 28.16 MB; used
    // 21.2 MB) — dead until k_final_q writes the real outputs.
    int2* binsAll2 = (int2*)d_out;                    // NBLK*CHUNK int2 capacity
    int*  hist2    = (int*)(binsAll2 + (size_t)NBLK * CHUNK);  // NE2 ints
    int*  hs2      = hist2 + NE2;                     // NE2+1 (+pad) ints

    float* out_ug  = out;
    float* out_ig  = out_ug  + (size_t)N_USERS * DD;
    float* out_img = out_ig  + (size_t)N_ITEMS * DD;
    float* out_txt = out_img + (size_t)N_ITEMS * DD;
    float* out_h   = out_txt + (size_t)N_ITEMS * DD;

    hipMemsetAsync(cnt_adj, 0, (size_t)(N_TOTAL + 2 * N_ITEMS) * sizeof(int), stream);

    ScanArg sa{(const int4*)cnt_adj, rp_adj, off_adj, N_TOTAL};
    ScanArg si{(const int4*)cnt_img, rp_img, off_img, N_ITEMS};
    ScanArg st{(const int4*)cnt_txt, rp_txt, off_txt, N_ITEMS};

    if (use16) {
        // ---- radix build: hist -> scans -> split -> hist2 -> scan -> split2 -> sort3
        k_hist<<<NBLK, 256, 0, stream>>>(adj_rows, adj_cols, img_rows, img_cols,
                                         txt_rows, txt_cols,
                                         cnt_adj, cnt_img, cnt_txt, hist);

        k_scan<<<3, 1024, 0, stream>>>(sa, si, st);

        ScanArg sh{(const int4*)hist, hs, hs, NBUCK * NBLK};
        k_scan<<<1, 1024, 0, stream>>>(sh, sh, sh);

        k_split<<<NBLK, 256, 0, stream>>>(adj_rows, adj_cols, adj_vals,
                                          img_rows, img_cols, img_vals,
                                          txt_rows, txt_cols, txt_vals,
                                          hs, binsAll);

        k_hist2<<<768, 256, 0, stream>>>(hs, binsAll, hist2);

        ScanArg sh2{(const int4*)hist2, hs2, hs2, NE2};
        k_scan<<<1, 1024, 0, stream>>>(sh2, sh2, sh2);

        k_split2<<<768, 256, 0, stream>>>(hs, hs2, binsAll, binsAll2);

        k_sort3<<<1344, 256, 0, stream>>>(hs2, binsAll2,
                                          rp_adj, rp_img, rp_txt,
                                          off_adj, off_img, off_txt,
                                          ep_adj, ep_img, ep_txt);

        // ---- fp16 gather tables (cached stores; binsAll now dead) ----
        k_cvt<<<2048, 256, 0, stream>>>(user_emb, item_emb, (unsigned short*)ego16);

        k_mm_q<TabF16><<<1875, 256, 0, stream>>>(
            rp_img, ep_img, rp_txt, ep_txt,
            TabF16{(const unsigned short*)ego16 + (size_t)N_USERS * DD, 0},
            Wq1, bq1, wq2, out_img, out_txt, out_h);

        k_spmm_ego_q<TabF16, true><<<6875, 256, 0, stream>>>(
            rp_adj, ep_adj, TabF16{(const unsigned short*)ego16, 0}, cur1, cur16);

        k_final_q<TabF16><<<NB_ITEM_FINAL + NB_USER_FINAL, 256, 0, stream>>>(
            rp_adj, ep_adj, TabF16{(const unsigned short*)cur16, 0}, cur1,
            user_emb, item_emb, out_h, Wc1, bc1, wc2, out_ug, out_ig);
    } else {
        // legacy build + f32 quad traversal fallback
        k_count_all<<<2048, 256, 0, stream>>>(adj_rows, img_rows, txt_rows,
                                              cnt_adj, cnt_img, cnt_txt);

        k_scan<<<3, 1024, 0, stream>>>(sa, si, st);

        k_scatter_all<<<2048, 256, 0, stream>>>(adj_rows, adj_cols, adj_vals,
                                                img_rows, img_cols, img_vals,
                                                txt_rows, txt_cols, txt_vals,
                                                off_adj, off_img, off_txt,
                                                ep_adj, ep_img, ep_txt);

        k_mm_q<TabF32><<<1875, 256, 0, stream>>>(
            rp_img, ep_img, rp_txt, ep_txt, TabF32{item_emb, 0},
            Wq1, bq1, wq2, out_img, out_txt, out_h);

        k_spmm_ego_q<TabEgo, false><<<6875, 256, 0, stream>>>(
            rp_adj, ep_adj, TabEgo{user_emb, item_emb, 0}, cur1, nullptr);

        k_final_q<TabF32><<<NB_ITEM_FINAL + NB_USER_FINAL, 256, 0, stream>>>(
            rp_adj, ep_adj, TabF32{cur1, 0}, cur1, user_emb, item_emb,
            out_h, Wc1, bc1, wc2, out_ug, out_ig);
    }
}

// Round 10
// 401.430 us; speedup vs baseline: 4.7119x; 1.3169x over previous
//
#include <hip/hip_runtime.h>
#include <hip/hip_fp16.h>

#define N_USERS 80000
#define N_ITEMS 30000
#define N_TOTAL 110000
#define DD 64
#define NNZ_ADJ 2000000
#define NNZ_MM 300000
#define TOTALE (NNZ_ADJ + 2 * NNZ_MM)

// row-partition divisors: 8 equal partitions (8*13750 = 110000, 8*3750 = 30000)
#define PART_ADJ 13750
#define PART_MM  3750

// radix-split geometry: 2048 blocks x contiguous CHUNK edges, 24 buckets
#define NBLK 2048
#define CHUNK 1270          // 2048*1270 = 2,600,960 >= TOTALE
#define NBUCK 24            // 3 matrices x 8 row-partitions

// level-2 fine buckets: 128-row windows
#define NSUB_ADJ 108        // ceil(13750/128)
#define NSUB_MM  30         // ceil(3750/128)
#define L2BLK 32            // level-2 blocks per (matrix,partition)
#define E_IMG0 (8 * NSUB_ADJ * L2BLK)            // 27648
#define E_TXT0 (E_IMG0 + 8 * NSUB_MM * L2BLK)    // 35328
#define NE2    (E_TXT0 + 8 * NSUB_MM * L2BLK)    // 43008 (divisible by 8)
#define SORT_CAP 4096       // LDS sort capacity (mean adj sub = 2327, std 48)

typedef float          f32x4 __attribute__((ext_vector_type(4)));
typedef unsigned short u16x4 __attribute__((ext_vector_type(4)));

// ---------------- non-temporal access helpers -------------------------------
// NT ONLY for truly read-once/write-once streams (round-6 lesson: nt is an
// LRU hint, it still allocates — reuse data must stay cached).
// Round-8 lesson: random sub-line stores cost ~a line of fabric write EACH.
// Round-9 lesson: device-scope atomics spread across XCDs onto a small
// counter array ping-pong lines between L2s (82 MB of fabric writes for a
// 680 KB array) — derive counts from scans instead of atomics wherever the
// pipeline already knows them.

__device__ __forceinline__ int   ntl(const int* p)   { return __builtin_nontemporal_load(p); }
__device__ __forceinline__ float ntl(const float* p) { return __builtin_nontemporal_load(p); }
__device__ __forceinline__ int2  ntl2(const int2* p)
{
    union { long long l; int2 v; } u;
    u.l = __builtin_nontemporal_load(reinterpret_cast<const long long*>(p));
    return u.v;
}
__device__ __forceinline__ void nts(float* p, float v) { __builtin_nontemporal_store(v, p); }

__device__ __forceinline__ unsigned short f2h(float f)
{
    __half h = __float2half(f);
    return *reinterpret_cast<unsigned short*>(&h);
}

// ---------------- diagnostic sentinel ---------------------------------------

__global__ void k_sentinel(float* out, float v)
{
    if (threadIdx.x == 0 && blockIdx.x == 0) out[0] = v;
}

// ======================= CSR construction ===================================
// Round-10 build: hist(no row atomics) -> scan -> split -> hist2 -> scan ->
// split2 -> sort3(writes rp itself). All allocation scan-based; ep and rp
// writes fully coalesced; zero per-row global atomics anywhere.

__device__ __forceinline__ bool decode_edge(
    int i,
    const int* __restrict__ ar, const int* __restrict__ ac,
    const int* __restrict__ ir, const int* __restrict__ ic,
    const int* __restrict__ tr, const int* __restrict__ tc,
    int& m, int& r, int& p, int& packed)
{
    if (i < NNZ_ADJ) {
        m = 0; r = ntl(ar + i); const int c = ntl(ac + i);
        if ((unsigned)r >= (unsigned)N_TOTAL || (unsigned)c >= (unsigned)N_TOTAL) return false;
        p = r / PART_ADJ; packed = ((r - p * PART_ADJ) << 17) | c;
    } else if (i < NNZ_ADJ + NNZ_MM) {
        const int j = i - NNZ_ADJ;
        m = 1; r = ntl(ir + j); const int c = ntl(ic + j);
        if ((unsigned)r >= (unsigned)N_ITEMS || (unsigned)c >= (unsigned)N_ITEMS) return false;
        p = r / PART_MM; packed = ((r - p * PART_MM) << 15) | c;
    } else {
        const int j = i - NNZ_ADJ - NNZ_MM;
        m = 2; r = ntl(tr + j); const int c = ntl(tc + j);
        if ((unsigned)r >= (unsigned)N_ITEMS || (unsigned)c >= (unsigned)N_ITEMS) return false;
        p = r / PART_MM; packed = ((r - p * PART_MM) << 15) | c;
    }
    return true;
}

// Pass A: per-block 24-bucket histogram (LDS only — no per-row counting).
__global__ __launch_bounds__(256) void k_hist(
    const int* __restrict__ ar, const int* __restrict__ ac,
    const int* __restrict__ ir, const int* __restrict__ ic,
    const int* __restrict__ tr, const int* __restrict__ tc,
    int* __restrict__ hist)
{
    __shared__ int h[NBUCK];
    if (threadIdx.x < NBUCK) h[threadIdx.x] = 0;
    __syncthreads();
    const int start = blockIdx.x * CHUNK;
    const int end   = min(start + CHUNK, TOTALE);
    for (int i = start + threadIdx.x; i < end; i += blockDim.x) {
        int m, r, p, packed;
        if (!decode_edge(i, ar, ac, ir, ic, tr, tc, m, r, p, packed)) continue;
        atomicAdd(&h[m * 8 + p], 1);
    }
    __syncthreads();
    if (threadIdx.x < NBUCK) hist[threadIdx.x * NBLK + blockIdx.x] = h[threadIdx.x];
}

// Pass C: re-read chunk, append to bucket regions at scanned bases.
__global__ __launch_bounds__(256) void k_split(
    const int* __restrict__ ar, const int* __restrict__ ac, const float* __restrict__ av,
    const int* __restrict__ ir, const int* __restrict__ ic, const float* __restrict__ iv,
    const int* __restrict__ tr, const int* __restrict__ tc, const float* __restrict__ tv,
    const int* __restrict__ hs, int2* __restrict__ binsAll)
{
    __shared__ int sb[NBUCK];
    if (threadIdx.x < NBUCK) sb[threadIdx.x] = hs[threadIdx.x * NBLK + blockIdx.x];
    __syncthreads();
    const int start = blockIdx.x * CHUNK;
    const int end   = min(start + CHUNK, TOTALE);
    for (int i = start + threadIdx.x; i < end; i += blockDim.x) {
        int m, r, p, packed;
        if (!decode_edge(i, ar, ac, ir, ic, tr, tc, m, r, p, packed)) continue;
        const float v = (m == 0) ? ntl(av + i)
                      : (m == 1) ? ntl(iv + (i - NNZ_ADJ))
                                 : ntl(tv + (i - NNZ_ADJ - NNZ_MM));
        const int idx = atomicAdd(&sb[m * 8 + p], 1);
        binsAll[idx] = make_int2(packed, __float_as_int(v));
    }
}

// ---- level-2: fine sub-bucketing (128-row windows) -------------------------
// 768 blocks: [0,256)=adj, [256,512)=img, [512,768)=txt; 32 blocks/(m,p).

__device__ __forceinline__ void l2_decode(int bid, int& q, int& b, int& nsub,
                                          int& cbits, int& e0)
{
    if (bid < 256)      { const int l = bid;       const int p = l >> 5; b = l & 31;
                          q = p;      nsub = NSUB_ADJ; cbits = 17; e0 = p * NSUB_ADJ * L2BLK; }
    else if (bid < 512) { const int l = bid - 256; const int p = l >> 5; b = l & 31;
                          q = 8 + p;  nsub = NSUB_MM;  cbits = 15; e0 = E_IMG0 + p * NSUB_MM * L2BLK; }
    else                { const int l = bid - 512; const int p = l >> 5; b = l & 31;
                          q = 16 + p; nsub = NSUB_MM;  cbits = 15; e0 = E_TXT0 + p * NSUB_MM * L2BLK; }
}

__global__ __launch_bounds__(256) void k_hist2(
    const int* __restrict__ hs, const int2* __restrict__ binsAll,
    int* __restrict__ hist2)
{
    __shared__ int h[NSUB_ADJ];
    int q, b, nsub, cbits, e0;
    l2_decode(blockIdx.x, q, b, nsub, cbits, e0);
    if (threadIdx.x < nsub) h[threadIdx.x] = 0;
    __syncthreads();
    const int beg = hs[q * NBLK], end = hs[(q + 1) * NBLK];
    const long long len = end - beg;
    const int c0 = beg + (int)((len * b) >> 5);
    const int c1 = beg + (int)((len * (b + 1)) >> 5);
    for (int i = c0 + threadIdx.x; i < c1; i += blockDim.x) {
        const int2 e = binsAll[i];
        atomicAdd(&h[((unsigned)e.x >> cbits) >> 7], 1);
    }
    __syncthreads();
    if (threadIdx.x < nsub) hist2[e0 + threadIdx.x * L2BLK + b] = h[threadIdx.x];
}

__global__ __launch_bounds__(256) void k_split2(
    const int* __restrict__ hs, const int* __restrict__ hs2,
    const int2* __restrict__ binsAll, int2* __restrict__ binsAll2)
{
    __shared__ int cur[NSUB_ADJ];
    int q, b, nsub, cbits, e0;
    l2_decode(blockIdx.x, q, b, nsub, cbits, e0);
    if (threadIdx.x < nsub) cur[threadIdx.x] = hs2[e0 + threadIdx.x * L2BLK + b];
    __syncthreads();
    const int beg = hs[q * NBLK], end = hs[(q + 1) * NBLK];
    const long long len = end - beg;
    const int c0 = beg + (int)((len * b) >> 5);
    const int c1 = beg + (int)((len * (b + 1)) >> 5);
    for (int i = c0 + threadIdx.x; i < c1; i += blockDim.x) {
        const int2 e = binsAll[i];
        const int s = ((unsigned)e.x >> cbits) >> 7;
        const int idx = atomicAdd(&cur[s], 1);
        binsAll2[idx] = e;   // ~nsub sequential append streams/block: lines fill
    }
}

// ---- level-3: per-sub-bucket LDS counting sort -> coalesced CSR write ------
// grid: 864 adj + 240 img + 240 txt = 1344 blocks. Also WRITES rp: sub-buckets
// are row-monotone per matrix, so rp[r0+rl] = (hs2[E] - matbase) + bas[rl].

__global__ __launch_bounds__(256) void k_sort3(
    const int* __restrict__ hs2, const int2* __restrict__ binsAll2,
    int* __restrict__ rpa, int* __restrict__ rpi, int* __restrict__ rpt,
    int2* __restrict__ ea, int2* __restrict__ ei, int2* __restrict__ et)
{
    __shared__ int2 sorted[SORT_CAP];
    __shared__ int cnt[128];
    __shared__ int bas[128];
    __shared__ int wsum[2];

    int p, s, E, cbits, partN, matE0, nrowsM; int* rp; int2* ep;
    const int bid = blockIdx.x;
    if (bid < 864) {
        p = bid / NSUB_ADJ; s = bid - p * NSUB_ADJ;
        E = (p * NSUB_ADJ + s) * L2BLK; cbits = 17; partN = PART_ADJ;
        matE0 = 0; nrowsM = N_TOTAL; rp = rpa; ep = ea;
    } else if (bid < 1104) {
        const int l = bid - 864; p = l / NSUB_MM; s = l - p * NSUB_MM;
        E = E_IMG0 + (p * NSUB_MM + s) * L2BLK; cbits = 15; partN = PART_MM;
        matE0 = E_IMG0; nrowsM = N_ITEMS; rp = rpi; ep = ei;
    } else {
        const int l = bid - 1104; p = l / NSUB_MM; s = l - p * NSUB_MM;
        E = E_TXT0 + (p * NSUB_MM + s) * L2BLK; cbits = 15; partN = PART_MM;
        matE0 = E_TXT0; nrowsM = N_ITEMS; rp = rpt; ep = et;
    }
    const int cmask = (1 << cbits) - 1;
    const int beg = hs2[E], end = hs2[E + L2BLK];
    const int matbase = hs2[matE0];
    const int n   = end - beg;
    const int r0  = p * partN + s * 128;
    const int tid = threadIdx.x;

    // ---- per-row count + exclusive prefix (always) ----
    if (tid < 128) cnt[tid] = 0;
    __syncthreads();
    for (int i = beg + tid; i < end; i += blockDim.x) {
        const int2 e = binsAll2[i];
        atomicAdd(&cnt[((unsigned)e.x >> cbits) - s * 128], 1);
    }
    __syncthreads();
    int x = 0;
    if (tid < 128) {
        x = cnt[tid];
        #pragma unroll
        for (int o = 1; o < 64; o <<= 1) {
            int t = __shfl_up(x, o);
            if ((tid & 63) >= o) x += t;
        }
        if ((tid & 63) == 63) wsum[tid >> 6] = x;
    }
    __syncthreads();
    if (tid < 128) {
        if (tid >= 64) x += wsum[0];
        bas[tid] = x - cnt[tid];     // exclusive prefix
    }
    __syncthreads();

    // ---- rp writes (coalesced; sub-buckets row-monotone per matrix) ----
    const int rpbase = beg - matbase;
    const int rows_here = min(128, partN - s * 128);
    if (tid < rows_here) rp[r0 + tid] = rpbase + bas[tid];
    // matrix-final block writes the sentinel rp[nrows]
    if (tid == 0 && (bid == 863 || bid == 1103 || bid == 1343))
        rp[nrowsM] = end - matbase;

    if (tid < 128) cnt[tid] = 0;     // reuse as cursor
    __syncthreads();

    if (n <= SORT_CAP) {
        for (int i = beg + tid; i < end; i += blockDim.x) {
            const int2 e = binsAll2[i];
            const int rl = ((unsigned)e.x >> cbits) - s * 128;
            const int pos = bas[rl] + atomicAdd(&cnt[rl], 1);
            sorted[pos] = e;
        }
        __syncthreads();
        for (int t = tid; t < n; t += blockDim.x) {
            const int2 e = sorted[t];
            ep[rpbase + t] = make_int2(e.x & cmask, e.y);   // coalesced
        }
    } else {
        // overflow fallback (statistically unreachable): direct scatter via
        // LDS cursors — still needs no global off arrays.
        for (int i = beg + tid; i < end; i += blockDim.x) {
            const int2 e = binsAll2[i];
            const int rl = ((unsigned)e.x >> cbits) - s * 128;
            const int pos = rpbase + bas[rl] + atomicAdd(&cnt[rl], 1);
            ep[pos] = make_int2(e.x & cmask, e.y);
        }
    }
}

// ---- legacy single-kernel build (fallback when ws lacks overlay room) ------

__global__ __launch_bounds__(256) void k_count_all(
    const int* __restrict__ ar, const int* __restrict__ ir,
    const int* __restrict__ tr,
    int* __restrict__ ca, int* __restrict__ ci, int* __restrict__ ct)
{
    const int total = TOTALE;
    for (int i = blockIdx.x * blockDim.x + threadIdx.x; i < total;
         i += gridDim.x * blockDim.x) {
        int r, lim; int* c;
        if (i < NNZ_ADJ)               { r = ntl(ar + i);                      c = ca; lim = N_TOTAL; }
        else if (i < NNZ_ADJ + NNZ_MM) { r = ntl(ir + (i - NNZ_ADJ));          c = ci; lim = N_ITEMS; }
        else                           { r = ntl(tr + (i - NNZ_ADJ - NNZ_MM)); c = ct; lim = N_ITEMS; }
        if ((unsigned)r < (unsigned)lim) atomicAdd(c + r, 1);
    }
}

__global__ __launch_bounds__(256) void k_scatter_all(
    const int* __restrict__ ar, const int* __restrict__ ac, const float* __restrict__ av,
    const int* __restrict__ ir, const int* __restrict__ ic, const float* __restrict__ iv,
    const int* __restrict__ tr, const int* __restrict__ tc, const float* __restrict__ tv,
    int* __restrict__ oa, int* __restrict__ oi, int* __restrict__ ot,
    int2* __restrict__ ea, int2* __restrict__ ei, int2* __restrict__ et)
{
    const int p     = blockIdx.x & 7;
    const int b8    = blockIdx.x >> 3;
    const int nb8   = gridDim.x >> 3;
    const int step  = nb8 * blockDim.x;

    for (int i0 = b8 * blockDim.x + threadIdx.x; i0 < TOTALE; i0 += step * 4) {
        #pragma unroll
        for (int u = 0; u < 4; ++u) {
            const int i = i0 + u * step;
            if (i >= TOTALE) break;
            int r, c, lim, part; float v; int* off; int2* ep;
            if (i < NNZ_ADJ) {
                r = ntl(ar + i);
                part = r / PART_ADJ;
                if (part != p) continue;
                c = ntl(ac + i); v = ntl(av + i); off = oa; ep = ea; lim = N_TOTAL;
            } else if (i < NNZ_ADJ + NNZ_MM) {
                const int j = i - NNZ_ADJ;
                r = ntl(ir + j);
                part = r / PART_MM;
                if (part != p) continue;
                c = ntl(ic + j); v = ntl(iv + j); off = oi; ep = ei; lim = N_ITEMS;
            } else {
                const int j = i - NNZ_ADJ - NNZ_MM;
                r = ntl(tr + j);
                part = r / PART_MM;
                if (part != p) continue;
                c = ntl(tc + j); v = ntl(tv + j); off = ot; ep = et; lim = N_ITEMS;
            }
            if ((unsigned)r >= (unsigned)lim || (unsigned)c >= (unsigned)lim) continue;
            const int pos = atomicAdd(&off[r], 1);
            ep[pos] = make_int2(c, __float_as_int(v));
        }
    }
}

struct ScanArg { const int4* cnt; int* rp; int* off; int n; };

// blocks pick a0/a1/a2; 8 elems/thread via int4; n must be divisible by 8.
__global__ __launch_bounds__(1024) void k_scan(ScanArg a0, ScanArg a1, ScanArg a2)
{
    ScanArg A = (blockIdx.x == 0) ? a0 : (blockIdx.x == 1) ? a1 : a2;
    __shared__ int swav[16];
    __shared__ int carry;
    const int lane = threadIdx.x & 63;
    const int wid  = threadIdx.x >> 6;
    if (threadIdx.x == 0) carry = 0;
    __syncthreads();

    for (int base = 0; base < A.n; base += 8192) {
        const int i0 = base + threadIdx.x * 8;
        int4 va = make_int4(0, 0, 0, 0), vb = make_int4(0, 0, 0, 0);
        if (i0 < A.n) { va = A.cnt[i0 >> 2]; vb = A.cnt[(i0 >> 2) + 1]; }
        const int tsum = va.x + va.y + va.z + va.w + vb.x + vb.y + vb.z + vb.w;

        int x = tsum;
        #pragma unroll
        for (int o = 1; o < 64; o <<= 1) {
            int t = __shfl_up(x, o);
            if (lane >= o) x += t;
        }
        if (lane == 63) swav[wid] = x;
        __syncthreads();
        if (wid == 0) {
            int y = (lane < 16) ? swav[lane] : 0;
            #pragma unroll
            for (int o = 1; o < 16; o <<= 1) {
                int t = __shfl_up(y, o);
                if (lane >= o) y += t;
            }
            if (lane < 16) swav[lane] = y;
        }
        __syncthreads();
        const int wbase = (wid > 0) ? swav[wid - 1] : 0;
        int e = carry + wbase + (x - tsum);

        int4 pa, pb;
        pa.x = e;            pa.y = pa.x + va.x;  pa.z = pa.y + va.y;  pa.w = pa.z + va.z;
        pb.x = pa.w + va.w;  pb.y = pb.x + vb.x;  pb.z = pb.y + vb.y;  pb.w = pb.z + vb.z;
        if (i0 < A.n) {
            ((int4*)A.rp)[i0 >> 2]        = pa;
            ((int4*)A.rp)[(i0 >> 2) + 1]  = pb;
            ((int4*)A.off)[i0 >> 2]       = pa;
            ((int4*)A.off)[(i0 >> 2) + 1] = pb;
        }
        const int tot = swav[15];
        __syncthreads();
        if (threadIdx.x == 0) carry += tot;
        __syncthreads();
    }
    if (threadIdx.x == 0) A.rp[A.n] = carry;
}

// ================== gather-table abstraction ================================
// UNIFORM base + lane member (round 6): col index arrives as an SGPR via
// readlane, so the gather compiles to saddr-form global_load.

struct TabF32 {
    const float* x; int lane;
    typedef float Raw;
    __device__ __forceinline__ Raw raw(int c) const { return x[(size_t)c * DD + lane]; }
    __device__ __forceinline__ static float cvt(Raw r) { return r; }
};
struct TabF16 {
    const unsigned short* x; int lane;
    typedef unsigned short Raw;
    __device__ __forceinline__ Raw raw(int c) const { return x[(size_t)c * DD + lane]; }
    __device__ __forceinline__ static float cvt(Raw r) {
        __half h; *reinterpret_cast<unsigned short*>(&h) = r;
        return __half2float(h);
    }
};
struct TabEgo {   // f32 fallback for layer-1 (split user/item tables)
    const float* u; const float* it; int lane;
    typedef float Raw;
    __device__ __forceinline__ Raw raw(int c) const {
        const float* b = (c < N_USERS) ? u + (size_t)c * DD
                                       : it + (size_t)(c - N_USERS) * DD;
        return b[lane];
    }
    __device__ __forceinline__ static float cvt(Raw r) { return r; }
};

// fp16 conversion of [user_emb; item_emb] -> ego16. CACHED stores (reused).
__global__ __launch_bounds__(256) void k_cvt(const float* __restrict__ ue,
                                             const float* __restrict__ ie,
                                             unsigned short* __restrict__ out)
{
    const int n0 = N_USERS * DD / 4;
    const int n1 = N_TOTAL * DD / 4;
    for (int i = blockIdx.x * blockDim.x + threadIdx.x; i < n1;
         i += gridDim.x * blockDim.x) {
        const f32x4 v = (i < n0)
            ? __builtin_nontemporal_load(((const f32x4*)ue) + i)
            : __builtin_nontemporal_load(((const f32x4*)ie) + (i - n0));
        u16x4 o;
        o.x = f2h(v.x); o.y = f2h(v.y); o.z = f2h(v.z); o.w = f2h(v.w);
        ((u16x4*)out)[i] = o;
    }
}

// ======================= CSR SpMM core ======================================
// Quad-row combined-range traversal (round 4) + scalar edge processing via
// readlane/readfirstlane (round 6). Unchanged from the verified 528 µs state.

template<typename T>
__device__ __forceinline__ void range8(const int2 e, int k0, int k1,
                                       const T& tab, float& acc)
{
    for (int k = k0; k < k1; k += 8) {
        float vs[8]; typename T::Raw xs[8];
        #pragma unroll
        for (int s = 0; s < 8; ++s) {
            const bool ok = (k + s) < k1;           // wave-uniform
            const int  ks = ok ? (k + s) : 0;       // valid lane id
            const int  cc = __builtin_amdgcn_readlane(e.x, ks);   // SGPR col
            const int  vv = __builtin_amdgcn_readlane(e.y, ks);   // SGPR val
            vs[s] = ok ? __int_as_float(vv) : 0.f;
            xs[s] = tab.raw(ok ? cc : 0);           // saddr gather
        }
        #pragma unroll
        for (int s = 0; s < 8; ++s) acc = fmaf(vs[s], T::cvt(xs[s]), acc);
    }
}

template<typename T>
__device__ __forceinline__ void csr_rows4(const int* __restrict__ rp,
                                          const int2* __restrict__ ep,
                                          const T& tab, int r0, int lane,
                                          float& oA, float& oB, float& oC, float& oD)
{
    const int4 qv = *(const int4*)(rp + r0);  // rp 16B-aligned, r0 % 4 == 0
    const int q0 = __builtin_amdgcn_readfirstlane(qv.x);
    const int q1 = __builtin_amdgcn_readfirstlane(qv.y);
    const int q2 = __builtin_amdgcn_readfirstlane(qv.z);
    const int q3 = __builtin_amdgcn_readfirstlane(qv.w);
    const int e4 = __builtin_amdgcn_readfirstlane(rp[r0 + 4]);
    float aA = 0.f, aB = 0.f, aC = 0.f, aD = 0.f;
    for (int j = q0; j < e4; j += 64) {
        const int cnt = min(64, e4 - j);
        int2 e = make_int2(0, 0);
        if (lane < cnt) e = ntl2(ep + j + lane);
        const int b1 = min(max(q1 - j, 0), cnt);
        const int b2 = min(max(q2 - j, 0), cnt);
        const int b3 = min(max(q3 - j, 0), cnt);
        range8(e, 0,  b1,  tab, aA);
        range8(e, b1, b2,  tab, aB);
        range8(e, b2, b3,  tab, aC);
        range8(e, b3, cnt, tab, aD);
    }
    oA = aA; oB = aB; oC = aC; oD = aD;
}

// -------- modality SpMM + attention fused: 4 items per wave -----------------

template<typename T>
__global__ __launch_bounds__(256) void k_mm_q(
    const int* __restrict__ rp_i, const int2* __restrict__ ep_i,
    const int* __restrict__ rp_t, const int2* __restrict__ ep_t,
    T tab,
    const float* __restrict__ Wq1, const float* __restrict__ bq1, const float* __restrict__ wq2,
    float* __restrict__ out_img, float* __restrict__ out_txt, float* __restrict__ out_h)
{
    __shared__ float sW[DD * DD];
    __shared__ float sb[DD];
    __shared__ float sq[DD];
    for (int i = threadIdx.x; i < DD * DD; i += blockDim.x) sW[i] = Wq1[i];
    if (threadIdx.x < DD) {
        sb[threadIdx.x] = bq1[threadIdx.x];
        sq[threadIdx.x] = wq2[threadIdx.x];
    }
    __syncthreads();

    const int lane = threadIdx.x & 63;
    const int i0 = (blockIdx.x * 4 + (threadIdx.x >> 6)) * 4;
    if (i0 >= N_ITEMS) return;
    tab.lane = lane;

    float iv[4], tv[4];
    csr_rows4(rp_i, ep_i, tab, i0, lane, iv[0], iv[1], iv[2], iv[3]);
    csr_rows4(rp_t, ep_t, tab, i0, lane, tv[0], tv[1], tv[2], tv[3]);
    #pragma unroll
    for (int q = 0; q < 4; ++q) {
        const size_t p = (size_t)(i0 + q) * DD + lane;
        nts(out_img + p, iv[q]);
        nts(out_txt + p, tv[q]);
    }

    // 8-stream MLP (4 items x {img, txt})
    float A0[4], A1[4];
    #pragma unroll
    for (int q = 0; q < 4; ++q) { A0[q] = sb[lane]; A1[q] = sb[lane]; }
    #pragma unroll 4
    for (int k = 0; k < DD; ++k) {
        const float w = sW[k * DD + lane];
        #pragma unroll
        for (int q = 0; q < 4; ++q) {
            A0[q] = fmaf(__shfl(iv[q], k), w, A0[q]);
            A1[q] = fmaf(__shfl(tv[q], k), w, A1[q]);
        }
    }
    #pragma unroll
    for (int q = 0; q < 4; ++q) {
        float si = tanhf(A0[q]) * sq[lane];
        float st = tanhf(A1[q]) * sq[lane];
        #pragma unroll
        for (int off = 32; off; off >>= 1) {
            si += __shfl_xor(si, off);
            st += __shfl_xor(st, off);
        }
        const float m  = fmaxf(si, st);
        const float ei = expf(si - m), et = expf(st - m);
        const size_t p = (size_t)(i0 + q) * DD + lane;
        nts(out_h + p, (ei * iv[q] + et * tv[q]) / (ei + et));
    }
}

// -------- cur1 = A * ego, 4 rows per wave; optional fp16 shadow copy --------

template<typename T, bool W16>
__global__ __launch_bounds__(256) void k_spmm_ego_q(
    const int* __restrict__ rp, const int2* __restrict__ ep, T tab,
    float* __restrict__ out, __half* __restrict__ out16)
{
    const int lane = threadIdx.x & 63;
    const int r0 = (blockIdx.x * 4 + (threadIdx.x >> 6)) * 4;
    if (r0 >= N_TOTAL) return;
    tab.lane = lane;
    float a, b, c, d;
    csr_rows4(rp, ep, tab, r0, lane, a, b, c, d);
    const size_t p = (size_t)r0 * DD + lane;
    nts(out + p,          a);
    nts(out + p + DD,     b);
    nts(out + p + 2 * DD, c);
    nts(out + p + 3 * DD, d);
    if constexpr (W16) {
        // CACHED: cur16 is gathered by k_final_q next
        out16[p]          = __float2half(a);
        out16[p + DD]     = __float2half(b);
        out16[p + 2 * DD] = __float2half(c);
        out16[p + 3 * DD] = __float2half(d);
    }
}

// -------- fused final: role-split blocks (item blocks first, VALU-heavy) ----

#define NB_ITEM_FINAL 1875   // 1875 blocks * 4 waves * 4 rows = 30000 items
#define NB_USER_FINAL 5000   // 5000 blocks * 4 waves * 4 rows = 80000 users

template<typename T>
__global__ __launch_bounds__(256) void k_final_q(
    const int* __restrict__ rp, const int2* __restrict__ ep, T tab,
    const float* __restrict__ cur1,
    const float* __restrict__ ue, const float* __restrict__ ie,
    const float* __restrict__ h_buf,
    const float* __restrict__ Wc1, const float* __restrict__ bc1, const float* __restrict__ wc2,
    float* __restrict__ out_ug, float* __restrict__ out_ig)
{
    __shared__ float sW[DD * DD];
    __shared__ float sb[DD];
    __shared__ float sq[DD];
    const int lane = threadIdx.x & 63;
    const int wv   = threadIdx.x >> 6;
    tab.lane = lane;

    if (blockIdx.x < NB_ITEM_FINAL) {
        for (int i = threadIdx.x; i < DD * DD; i += blockDim.x) sW[i] = Wc1[i];
        if (threadIdx.x < DD) {
            sb[threadIdx.x] = bc1[threadIdx.x];
            sq[threadIdx.x] = wc2[threadIdx.x];
        }
        __syncthreads();

        const int i0 = (blockIdx.x * 4 + wv) * 4;     // item index base
        const int r0 = N_USERS + i0;
        float a[4];
        csr_rows4(rp, ep, tab, r0, lane, a[0], a[1], a[2], a[3]);

        float ig[4], hn[4];
        #pragma unroll
        for (int q = 0; q < 4; ++q) {
            const size_t pb = (size_t)(i0 + q) * DD + lane;
            const size_t gb = (size_t)(r0 + q) * DD + lane;
            ig[q] = (ntl(ie + pb) + ntl(cur1 + gb) + a[q]) * (1.0f / 3.0f);
            const float hv = ntl(h_buf + pb);
            float ss = hv * hv;
            #pragma unroll
            for (int off = 32; off; off >>= 1) ss += __shfl_xor(ss, off);
            hn[q] = hv / fmaxf(sqrtf(ss), 1e-12f);
        }

        float A0[4], A1[4];
        #pragma unroll
        for (int q = 0; q < 4; ++q) { A0[q] = sb[lane]; A1[q] = sb[lane]; }
        #pragma unroll 4
        for (int k = 0; k < DD; ++k) {
            const float w = sW[k * DD + lane];
            #pragma unroll
            for (int q = 0; q < 4; ++q) {
                A0[q] = fmaf(__shfl(ig[q], k), w, A0[q]);
                A1[q] = fmaf(__shfl(hn[q], k), w, A1[q]);
            }
        }
        #pragma unroll
        for (int q = 0; q < 4; ++q) {
            float s0 = tanhf(A0[q]) * sq[lane];
            float s1 = tanhf(A1[q]) * sq[lane];
            #pragma unroll
            for (int off = 32; off; off >>= 1) {
                s0 += __shfl_xor(s0, off);
                s1 += __shfl_xor(s1, off);
            }
            const float m  = fmaxf(s0, s1);
            const float e0 = expf(s0 - m), e1 = expf(s1 - m);
            nts(out_ig + (size_t)(i0 + q) * DD + lane,
                (e0 * ig[q] + e1 * hn[q]) / (e0 + e1));
        }
    } else {
        const int r0 = ((blockIdx.x - NB_ITEM_FINAL) * 4 + wv) * 4;   // user rows
        float a[4];
        csr_rows4(rp, ep, tab, r0, lane, a[0], a[1], a[2], a[3]);
        #pragma unroll
        for (int q = 0; q < 4; ++q) {
            const size_t gb = (size_t)(r0 + q) * DD + lane;
            nts(out_ug + gb, (ntl(ue + gb) + ntl(cur1 + gb) + a[q]) * (1.0f / 3.0f));
        }
    }
}

// ----------------------------------------------------------------------------

extern "C" void kernel_launch(void* const* d_in, const int* in_sizes, int n_in,
                              void* d_out, int out_size, void* d_ws, size_t ws_size,
                              hipStream_t stream)
{
    static const int EXP[17] = {
        N_USERS * DD, N_ITEMS * DD, DD * DD, DD, DD, DD * DD, DD, DD,
        NNZ_ADJ, NNZ_MM, NNZ_MM, NNZ_ADJ, NNZ_ADJ, NNZ_MM, NNZ_MM, NNZ_MM, NNZ_MM
    };

    float* out = (float*)d_out;

    const int OUT_EXPECT = (N_USERS + 4 * N_ITEMS) * DD;
    if (out_size != OUT_EXPECT) {
        k_sentinel<<<1, 64, 0, stream>>>(out, 5000.0f + (float)(((unsigned)out_size) >> 20));
        return;
    }
    if (n_in < 17) {
        k_sentinel<<<1, 64, 0, stream>>>(out, 1000.0f + 8.0f * (float)n_in);
        return;
    }

    int map[17];
    bool exact = true;
    for (int i = 0; i < 17; ++i) { map[i] = i; if (in_sizes[i] != EXP[i]) exact = false; }
    if (!exact) {
        bool used[64] = {false};
        for (int i = 0; i < 17; ++i) {
            int found = -1;
            for (int j = 0; j < n_in && j < 64; ++j)
                if (!used[j] && in_sizes[j] == EXP[i]) { found = j; break; }
            if (found < 0) {
                k_sentinel<<<1, 64, 0, stream>>>(out, 2000.0f + 32.0f * (float)i);
                return;
            }
            used[found] = true; map[i] = found;
        }
    }

    const float* user_emb = (const float*)d_in[map[0]];
    const float* item_emb = (const float*)d_in[map[1]];
    const float* Wq1      = (const float*)d_in[map[2]];
    const float* bq1      = (const float*)d_in[map[3]];
    const float* wq2      = (const float*)d_in[map[4]];
    const float* Wc1      = (const float*)d_in[map[5]];
    const float* bc1      = (const float*)d_in[map[6]];
    const float* wc2      = (const float*)d_in[map[7]];
    const float* adj_vals = (const float*)d_in[map[8]];
    const float* img_vals = (const float*)d_in[map[9]];
    const float* txt_vals = (const float*)d_in[map[10]];
    const int* adj_rows   = (const int*)d_in[map[11]];
    const int* adj_cols   = (const int*)d_in[map[12]];
    const int* img_rows   = (const int*)d_in[map[13]];
    const int* img_cols   = (const int*)d_in[map[14]];
    const int* txt_rows   = (const int*)d_in[map[15]];
    const int* txt_cols   = (const int*)d_in[map[16]];

    // -------- workspace layout (all 16B-aligned sections) --------
    float* cur1   = (float*)d_ws;                     // N_TOTAL*DD
    int2*  ep_adj = (int2*)(cur1 + (size_t)N_TOTAL * DD);
    int2*  ep_img = ep_adj + NNZ_ADJ;
    int2*  ep_txt = ep_img + NNZ_MM;
    int*   cnt_adj = (int*)(ep_txt + NNZ_MM);         // contiguous cnt block
    int*   cnt_img = cnt_adj + N_TOTAL;
    int*   cnt_txt = cnt_img + N_ITEMS;
    int*   rp_adj  = cnt_txt + N_ITEMS;               // padded to keep 16B align
    int*   rp_img  = rp_adj + 110004;
    int*   rp_txt  = rp_img + 30004;
    int*   off_adj = rp_txt + 30004;
    int*   off_img = off_adj + N_TOTAL;
    int*   off_txt = off_img + N_ITEMS;
    int*   hist    = off_txt + N_ITEMS;               // NBUCK*NBLK = 49152 ints
    int*   hs      = hist + NBUCK * NBLK;             // 49153 (+3 pad) ints
    int*   i_end   = hs + NBUCK * NBLK + 4;

    size_t used_b = (size_t)((char*)i_end - (char*)d_ws);
    if (ws_size < used_b) {
        k_sentinel<<<1, 64, 0, stream>>>(out, 3000.0f + (float)(ws_size >> 20));
        return;
    }
    used_b = (used_b + 15) & ~(size_t)15;
    __half* ego16 = (__half*)((char*)d_ws + used_b);          // N_TOTAL*DD halves
    __half* cur16 = ego16 + (size_t)N_TOTAL * DD;             // N_TOTAL*DD halves
    const size_t WS_FULL = used_b + 2 * (size_t)N_TOTAL * DD * sizeof(__half);
    const bool use16 = (ws_size >= WS_FULL);

    // binsAll OVERLAYS the ego16/cur16 region (28.16 MB; needs 20.8 MB);
    // dead before k_cvt writes ego16.
    int2* binsAll = (int2*)ego16;

    // level-2 scratch lives in d_out (out_ug+out_ig region, 28.16 MB; used
    // 21.2 MB) — dead until k_final_q writes the real outputs.
    int2* binsAll2 = (int2*)d_out;                    // NBLK*CHUNK int2 capacity
    int*  hist2    = (int*)(binsAll2 + (size_t)NBLK * CHUNK);  // NE2 ints
    int*  hs2      = hist2 + NE2;                     // NE2+1 (+pad) ints

    float* out_ug  = out;
    float* out_ig  = out_ug  + (size_t)N_USERS * DD;
    float* out_img = out_ig  + (size_t)N_ITEMS * DD;
    float* out_txt = out_img + (size_t)N_ITEMS * DD;
    float* out_h   = out_txt + (size_t)N_ITEMS * DD;

    ScanArg sa{(const int4*)cnt_adj, rp_adj, off_adj, N_TOTAL};
    ScanArg si{(const int4*)cnt_img, rp_img, off_img, N_ITEMS};
    ScanArg st{(const int4*)cnt_txt, rp_txt, off_txt, N_ITEMS};

    if (use16) {
        // ---- radix build: hist -> scan -> split -> hist2 -> scan -> split2
        //      -> sort3 (writes ep AND rp; no per-row atomics anywhere) ----
        k_hist<<<NBLK, 256, 0, stream>>>(adj_rows, adj_cols, img_rows, img_cols,
                                         txt_rows, txt_cols, hist);

        ScanArg sh{(const int4*)hist, hs, hs, NBUCK * NBLK};
        k_scan<<<1, 1024, 0, stream>>>(sh, sh, sh);

        k_split<<<NBLK, 256, 0, stream>>>(adj_rows, adj_cols, adj_vals,
                                          img_rows, img_cols, img_vals,
                                          txt_rows, txt_cols, txt_vals,
                                          hs, binsAll);

        k_hist2<<<768, 256, 0, stream>>>(hs, binsAll, hist2);

        ScanArg sh2{(const int4*)hist2, hs2, hs2, NE2};
        k_scan<<<1, 1024, 0, stream>>>(sh2, sh2, sh2);

        k_split2<<<768, 256, 0, stream>>>(hs, hs2, binsAll, binsAll2);

        k_sort3<<<1344, 256, 0, stream>>>(hs2, binsAll2,
                                          rp_adj, rp_img, rp_txt,
                                          ep_adj, ep_img, ep_txt);

        // ---- fp16 gather tables (cached stores; binsAll now dead) ----
        k_cvt<<<2048, 256, 0, stream>>>(user_emb, item_emb, (unsigned short*)ego16);

        k_mm_q<TabF16><<<1875, 256, 0, stream>>>(
            rp_img, ep_img, rp_txt, ep_txt,
            TabF16{(const unsigned short*)ego16 + (size_t)N_USERS * DD, 0},
            Wq1, bq1, wq2, out_img, out_txt, out_h);

        k_spmm_ego_q<TabF16, true><<<6875, 256, 0, stream>>>(
            rp_adj, ep_adj, TabF16{(const unsigned short*)ego16, 0}, cur1, cur16);

        k_final_q<TabF16><<<NB_ITEM_FINAL + NB_USER_FINAL, 256, 0, stream>>>(
            rp_adj, ep_adj, TabF16{(const unsigned short*)cur16, 0}, cur1,
            user_emb, item_emb, out_h, Wc1, bc1, wc2, out_ug, out_ig);
    } else {
        // legacy build + f32 quad traversal fallback
        hipMemsetAsync(cnt_adj, 0, (size_t)(N_TOTAL + 2 * N_ITEMS) * sizeof(int), stream);

        k_count_all<<<2048, 256, 0, stream>>>(adj_rows, img_rows, txt_rows,
                                              cnt_adj, cnt_img, cnt_txt);

        k_scan<<<3, 1024, 0, stream>>>(sa, si, st);

        k_scatter_all<<<2048, 256, 0, stream>>>(adj_rows, adj_cols, adj_vals,
                                                img_rows, img_cols, img_vals,
                                                txt_rows, txt_cols, txt_vals,
                                                off_adj, off_img, off_txt,
                                                ep_adj, ep_img, ep_txt);

        k_mm_q<TabF32><<<1875, 256, 0, stream>>>(
            rp_img, ep_img, rp_txt, ep_txt, TabF32{item_emb, 0},
            Wq1, bq1, wq2, out_img, out_txt, out_h);

        k_spmm_ego_q<TabEgo, false><<<6875, 256, 0, stream>>>(
            rp_adj, ep_adj, TabEgo{user_emb, item_emb, 0}, cur1, nullptr);

        k_final_q<TabF32><<<NB_ITEM_FINAL + NB_USER_FINAL, 256, 0, stream>>>(
            rp_adj, ep_adj, TabF32{cur1, 0}, cur1, user_emb, item_emb,
            out_h, Wc1, bc1, wc2, out_ug, out_ig);
    }
}